// Round 6
// baseline (12894.736 us; speedup 1.0000x reference)
//
#include <hip/hip_runtime.h>

// ============================================================================
// Seq2Seq (bi-LSTM encoder + Bahdanau-attention LSTM decoder) on gfx950.
// fp32 in/out; fp16 internal (fp32 accum/state).
// R17 = R16 (12.46 ms) + full-row attention, partials machinery deleted:
//   Decode was 66 us/step vs ~20 us of modeled work.  Root-cause candidate:
//   the gates prologue (softmax combine) was computed 16x redundantly --
//   16 j-blocks on different XCDs re-reading 8 MB/step of part_ctx and
//   storing the SAME x_sw cachelines (cross-XCD coherence storm).
//   Fix: attention = 128 blocks x 1024 thr (16 waves x 32 s-rows); each
//   block owns a full batch row: complete softmax (local M, l) + normalized
//   ctx written DIRECTLY to x_sw.  part_m/part_l/part_ctx + gm/combine are
//   gone.  Gates phase = pure GEMM+LSTM+qGEMM.  k_step fusion + p2p flags
//   kept (32 producers -> 128 private consumer lines), grid 160 x 1024.
//   k_enc unchanged from R16 (3.51 ms, separate battle).
// ============================================================================

typedef _Float16 f16;
typedef _Float16 half8 __attribute__((ext_vector_type(8)));
typedef float f32x4 __attribute__((ext_vector_type(4)));
typedef char char8v __attribute__((ext_vector_type(8)));

#define MFMA16(a, b, c) __builtin_amdgcn_mfma_f32_16x16x32_f16((a), (b), (c), 0, 0, 0)

#define PSCALE (2.5f / 127.f)      // int8 proj dequant scale
#define PINV   (127.f / 2.5f)      // quant scale

__device__ __forceinline__ float fsig(float x) {
    return __builtin_amdgcn_rcpf(1.f + __expf(-x));
}
__device__ __forceinline__ float ftanh(float x) {
    return 1.f - 2.f * __builtin_amdgcn_rcpf(1.f + __expf(2.f * x));
}
__device__ __forceinline__ int frag_idx(int m, int k, int KS) {
    return (((m >> 4) * KS + (k >> 5)) * 64 + (((k >> 3) & 3) * 16 + (m & 15))) * 8 + (k & 7);
}

// LDS-only barrier: waits own-wave LDS ops, then barrier.  Deliberately does
// NOT drain vmcnt -- global stores/prefetches stay in flight across steps.
__device__ __forceinline__ void lds_barrier() {
    asm volatile("s_waitcnt lgkmcnt(0)" ::: "memory");
    __builtin_amdgcn_sched_barrier(0);
    __builtin_amdgcn_s_barrier();
    __builtin_amdgcn_sched_barrier(0);
}

// ---------------------------------------------------------------------------
// K_zero: reset flag region (each graph replay).  flags[0] = arrival counter;
// flags[16 + i*16] = private ready-word for attention block i (i < 128).
// ---------------------------------------------------------------------------
__global__ void k_zero(unsigned* __restrict__ s)
{
    for (int z = threadIdx.x; z < 4112; z += 256) s[z] = 0u;
}

// ---------------------------------------------------------------------------
// K0: one-shot: pack weights to fragment order (f32 -> f16), plain converts,
// zero out t=0 output row.
// ---------------------------------------------------------------------------
__global__ __launch_bounds__(256) void k_prep(
    const float* __restrict__ attn_W, const float* __restrict__ out_W,
    const float* __restrict__ enc_emb,
    const float* __restrict__ wihf, const float* __restrict__ wihb,
    const float* __restrict__ whhf, const float* __restrict__ whhb,
    const float* __restrict__ dec_emb, const float* __restrict__ dec_wih,
    const float* __restrict__ dec_whh,
    f16* __restrict__ WhT_sw, f16* __restrict__ outWT_sw,
    f16* __restrict__ whhf_sw, f16* __restrict__ whhb_sw,
    f16* __restrict__ decwih_sw, f16* __restrict__ decwhh_sw,
    f16* __restrict__ WeT, f16* __restrict__ emb16,
    f16* __restrict__ wihf16, f16* __restrict__ wihb16,
    f16* __restrict__ decemb16, float* __restrict__ out)
{
    long i = (long)blockIdx.x * 256 + threadIdx.x;
    if (i >= 3784704L) return;
    long idx = i;
    if (idx < 262144) {  // WhT_sw: N=512(e) x K=512(d)
        int j = idx & 7, lane = (idx >> 3) & 63, c = lane & 15, q = lane >> 4;
        int ks = (idx >> 9) & 15, nt = idx >> 13;
        WhT_sw[idx] = (f16)attn_W[(ks * 32 + q * 8 + j) * 512 + nt * 16 + c];
        return;
    }
    idx -= 262144;
    if (idx < 65536) {   // outWT_sw: N=128(v) x K=512(d)
        int j = idx & 7, lane = (idx >> 3) & 63, c = lane & 15, q = lane >> 4;
        int ks = (idx >> 9) & 15, nt = idx >> 13;
        outWT_sw[idx] = (f16)out_W[(ks * 32 + q * 8 + j) * 128 + nt * 16 + c];
        return;
    }
    idx -= 65536;
    if (idx < 262144) {  // whhf_sw: N=1024 x K=256
        int j = idx & 7, lane = (idx >> 3) & 63, c = lane & 15, q = lane >> 4;
        int ks = (idx >> 9) & 7, nt = idx >> 12;
        whhf_sw[idx] = (f16)whhf[(nt * 16 + c) * 256 + ks * 32 + q * 8 + j];
        return;
    }
    idx -= 262144;
    if (idx < 262144) {  // whhb_sw
        int j = idx & 7, lane = (idx >> 3) & 63, c = lane & 15, q = lane >> 4;
        int ks = (idx >> 9) & 7, nt = idx >> 12;
        whhb_sw[idx] = (f16)whhb[(nt * 16 + c) * 256 + ks * 32 + q * 8 + j];
        return;
    }
    idx -= 262144;
    if (idx < 1310720) { // decwih_sw: N=2048 x K=640
        int j = idx & 7, lane = (idx >> 3) & 63, c = lane & 15, q = lane >> 4;
        int r2 = idx >> 9; int ks = r2 % 20, nt = r2 / 20;
        decwih_sw[idx] = (f16)dec_wih[(nt * 16 + c) * 640 + ks * 32 + q * 8 + j];
        return;
    }
    idx -= 1310720;
    if (idx < 1048576) { // decwhh_sw: N=2048 x K=512
        int j = idx & 7, lane = (idx >> 3) & 63, c = lane & 15, q = lane >> 4;
        int ks = (idx >> 9) & 15, nt = idx >> 13;
        decwhh_sw[idx] = (f16)dec_whh[(nt * 16 + c) * 512 + ks * 32 + q * 8 + j];
        return;
    }
    idx -= 1048576;
    if (idx < 262144) { int e = idx >> 9, d = idx & 511; WeT[idx] = (f16)attn_W[(512 + d) * 512 + e]; return; }
    idx -= 262144;
    if (idx < 16384)  { emb16[idx] = (f16)enc_emb[idx]; return; }
    idx -= 16384;
    if (idx < 131072) { wihf16[idx] = (f16)wihf[idx]; return; }
    idx -= 131072;
    if (idx < 131072) { wihb16[idx] = (f16)wihb[idx]; return; }
    idx -= 131072;
    if (idx < 16384)  { decemb16[idx] = (f16)dec_emb[idx]; return; }
    idx -= 16384;
    if (idx < 16384)  { int b = idx >> 7, v = idx & 127; out[b * 16384 + v] = 0.f; return; }
}

// ---------------------------------------------------------------------------
// K_vocab: xg_vocab[v][n] = emb[v] @ [Wih_f|Wih_b]^T + [b_f|b_b] (once).
// ---------------------------------------------------------------------------
__global__ __launch_bounds__(256) void k_vocab(
    const f16* __restrict__ emb, const f16* __restrict__ wihf,
    const f16* __restrict__ wihb, const float* __restrict__ bf_,
    const float* __restrict__ bb_, f16* __restrict__ xg_vocab)
{
    int bn = blockIdx.x;
    int tid = threadIdx.x, wave = tid >> 6, lane = tid & 63;
    int col = lane & 15, quad = lane >> 4;
    int wr = wave >> 1, wc = wave & 1;

    f32x4 acc[4][4] = {};
    for (int ks = 0; ks < 4; ++ks) {
        int k0 = ks * 32 + quad * 8;
        half8 a[4], bfr[4];
        for (int i = 0; i < 4; ++i)
            a[i] = *(const half8*)(emb + (wr * 64 + i * 16 + col) * 128 + k0);
        for (int j = 0; j < 4; ++j) {
            int n = bn * 128 + wc * 64 + j * 16 + col;
            const f16* wp = (n < 1024) ? (wihf + n * 128) : (wihb + (n - 1024) * 128);
            bfr[j] = *(const half8*)(wp + k0);
        }
        for (int i = 0; i < 4; ++i)
            for (int j = 0; j < 4; ++j)
                acc[i][j] = MFMA16(a[i], bfr[j], acc[i][j]);
    }
    for (int j = 0; j < 4; ++j) {
        int n = bn * 128 + wc * 64 + j * 16 + col;
        float bias = (n < 1024) ? bf_[n] : bb_[n - 1024];
        for (int i = 0; i < 4; ++i) {
            int vbase = wr * 64 + i * 16 + quad * 4;
            for (int r = 0; r < 4; ++r)
                xg_vocab[(vbase + r) * 2048 + n] = (f16)(acc[i][j][r] + bias);
        }
    }
}

// ---------------------------------------------------------------------------
// K_enc (R16 form): encoder scan, 16 blocks, 512 threads, one lgkm-only
// barrier per t-step; hb/xvb double-buffered; no vmcnt drain in-loop.
// ---------------------------------------------------------------------------
__global__ __launch_bounds__(512, 1) void k_enc(
    const int* __restrict__ src, const f16* __restrict__ xg_vocab,
    const f16* __restrict__ whhf_sw, const f16* __restrict__ whhb_sw,
    f16* __restrict__ enc_out, f16* __restrict__ hdec0, float* __restrict__ c_ws)
{
    int blk = blockIdx.x;
    int dir = blk >> 3, bbase = (blk & 7) * 16;
    int tid = threadIdx.x, wave = tid >> 6, lane = tid & 63;
    int col = lane & 15, quad = lane >> 4;
    const f16* whh = dir ? whhb_sw : whhf_sw;

    __shared__ f16 hb[2][16][264];
    __shared__ f16 xvb[2][16][1032];
    __shared__ unsigned short stall[8192];   // [b][t] tokens (VIN=128 fits u16)

    for (int z = tid; z < 2 * 16 * 264; z += 512) ((f16*)hb)[z] = (f16)0.f;
    for (int z = tid; z < 8192; z += 512) stall[z] = (unsigned short)src[bbase * 512 + z];
    float cc[2][4] = {};

    // gate-0 Whh fragments resident in VGPRs: 16 half8 = 64 VGPR
    half8 bst[16];
    #pragma unroll
    for (int nt = 0; nt < 2; ++nt)
        #pragma unroll
        for (int kk = 0; kk < 8; ++kk) {
            int tile = wave * 2 + nt;
            bst[nt * 8 + kk] = *(const half8*)(whh + ((tile * 8 + kk) * 64 + lane) * 8);
        }
    __syncthreads();

    int xrow = tid >> 7, xoff = (tid & 127) * 8;
    half8 xr[4];
    {
        int ts0 = dir ? 511 : 0;
        #pragma unroll
        for (int it = 0; it < 4; ++it) {
            int row = it * 4 + xrow;
            int tok = stall[row * 512 + ts0];
            xr[it] = *(const half8*)(xg_vocab + tok * 2048 + dir * 1024 + xoff);
        }
        #pragma unroll
        for (int it = 0; it < 4; ++it)
            *(half8*)(&xvb[0][it * 4 + xrow][xoff]) = xr[it];
    }
    __syncthreads();

    int ts_prev = 0;
    for (int t = 0; t < 512; ++t) {
        int ts = dir ? (511 - t) : t;
        int cur = t & 1, prv = cur ^ 1;

        if (t < 511) {
            int tsn = dir ? (510 - t) : (t + 1);
            #pragma unroll
            for (int it = 0; it < 4; ++it) {
                int row = it * 4 + xrow;
                int tok = stall[row * 512 + tsn];
                xr[it] = *(const half8*)(xg_vocab + tok * 2048 + dir * 1024 + xoff);
            }
        }

        if (t > 0) {
            int b = tid >> 5, seg = tid & 31;
            *(half8*)(enc_out + ((size_t)(bbase + b) * 512 + ts_prev) * 512 + dir * 256 + seg * 8) =
                *(const half8*)(&hb[prv][b][seg * 8]);
        }

        half8 a[8];
        #pragma unroll
        for (int kk = 0; kk < 8; ++kk)
            a[kk] = *(const half8*)(&hb[prv][col][kk * 32 + quad * 8]);

        f32x4 acc[4][2] = {};
        #pragma unroll
        for (int kk = 0; kk < 8; ++kk) {
            half8 bv[6];
            #pragma unroll
            for (int g = 1; g < 4; ++g)
                #pragma unroll
                for (int nt = 0; nt < 2; ++nt) {
                    int tile = g * 16 + wave * 2 + nt;
                    bv[(g - 1) * 2 + nt] =
                        *(const half8*)(whh + ((tile * 8 + kk) * 64 + lane) * 8);
                }
            #pragma unroll
            for (int nt = 0; nt < 2; ++nt)
                acc[0][nt] = MFMA16(a[kk], bst[nt * 8 + kk], acc[0][nt]);
            #pragma unroll
            for (int g = 1; g < 4; ++g)
                #pragma unroll
                for (int nt = 0; nt < 2; ++nt)
                    acc[g][nt] = MFMA16(a[kk], bv[(g - 1) * 2 + nt], acc[g][nt]);
        }

        #pragma unroll
        for (int nt = 0; nt < 2; ++nt) {
            int hcol = wave * 32 + nt * 16 + col;
            #pragma unroll
            for (int r = 0; r < 4; ++r) {
                int b = quad * 4 + r;
                float gi = (float)xvb[cur][b][0 * 256 + hcol] + acc[0][nt][r];
                float gf = (float)xvb[cur][b][1 * 256 + hcol] + acc[1][nt][r];
                float gg = (float)xvb[cur][b][2 * 256 + hcol] + acc[2][nt][r];
                float go = (float)xvb[cur][b][3 * 256 + hcol] + acc[3][nt][r];
                float ig = fsig(gi), fg = fsig(gf), g2 = ftanh(gg), og = fsig(go);
                float cv = fg * cc[nt][r] + ig * g2;
                cc[nt][r] = cv;
                float h = og * ftanh(cv);
                hb[cur][b][hcol] = (f16)h;
            }
        }

        if (t < 511) {
            #pragma unroll
            for (int it = 0; it < 4; ++it)
                *(half8*)(&xvb[prv][it * 4 + xrow][xoff]) = xr[it];
        }

        lds_barrier();
        ts_prev = ts;
    }

    {
        int b = tid >> 5, seg = tid & 31;
        *(half8*)(enc_out + ((size_t)(bbase + b) * 512 + ts_prev) * 512 + dir * 256 + seg * 8) =
            *(const half8*)(&hb[1][b][seg * 8]);
    }
    #pragma unroll
    for (int nt = 0; nt < 2; ++nt) {
        int hcol = wave * 32 + nt * 16 + col;
        #pragma unroll
        for (int r = 0; r < 4; ++r) {
            int b = quad * 4 + r;
            int m = bbase + b, k = dir * 256 + hcol;
            hdec0[frag_idx(m, k, 16)] = hb[1][b][hcol];
            c_ws[m * 512 + k] = cc[nt][r];
        }
    }
}

// ---------------------------------------------------------------------------
// K_proj: enc_proj = enc_out @ We (once).  Writes int8 (fixed scale).
// ---------------------------------------------------------------------------
__global__ __launch_bounds__(256) void k_proj(
    const f16* __restrict__ enc_out, const f16* __restrict__ WeT,
    char* __restrict__ proj8)
{
    int blk = blockIdx.x;
    int bm = blk & 511, bn = blk >> 9;
    int tid = threadIdx.x, wave = tid >> 6, lane = tid & 63;
    int col = lane & 15, quad = lane >> 4;
    int wr = wave >> 1, wc = wave & 1;

    f32x4 acc[4][4] = {};
    for (int ks = 0; ks < 16; ++ks) {
        int k0 = ks * 32 + quad * 8;
        half8 a[4], bfr[4];
        for (int i = 0; i < 4; ++i) {
            int m = bm * 128 + wr * 64 + i * 16 + col;
            a[i] = *(const half8*)(enc_out + (size_t)m * 512 + k0);
        }
        for (int j = 0; j < 4; ++j) {
            int n = bn * 128 + wc * 64 + j * 16 + col;
            bfr[j] = *(const half8*)(WeT + n * 512 + k0);
        }
        for (int i = 0; i < 4; ++i)
            for (int j = 0; j < 4; ++j)
                acc[i][j] = MFMA16(a[i], bfr[j], acc[i][j]);
    }
    for (int j = 0; j < 4; ++j) {
        int n = bn * 128 + wc * 64 + j * 16 + col;
        for (int i = 0; i < 4; ++i) {
            int mbase = bm * 128 + wr * 64 + i * 16 + quad * 4;
            for (int r = 0; r < 4; ++r) {
                float v = acc[i][j][r] * PINV;
                int q = (int)rintf(v);
                q = (q > 127) ? 127 : ((q < -127) ? -127 : q);
                proj8[(size_t)(mbase + r) * 512 + n] = (char)q;
            }
        }
    }
}

// ---------------------------------------------------------------------------
// K_qinit: initial q-partials (once).
// ---------------------------------------------------------------------------
__global__ __launch_bounds__(256) void k_qinit(
    const f16* __restrict__ h0_sw, const f16* __restrict__ WhT_sw,
    float* __restrict__ qpart)
{
    int j = blockIdx.x;
    int tid = threadIdx.x, wave = tid >> 6, lane = tid & 63;
    int col = lane & 15, quad = lane >> 4;
    half8 a[2];
    #pragma unroll
    for (int i = 0; i < 2; ++i)
        a[i] = *(const half8*)(h0_sw + (((wave * 2 + i) * 16 + j) * 64 + lane) * 8);
    for (int nt = 0; nt < 32; ++nt) {
        half8 bfr = *(const half8*)(WhT_sw + ((nt * 16 + j) * 64 + lane) * 8);
        f32x4 q0 = {}, q1 = {};
        q0 = MFMA16(a[0], bfr, q0);
        q1 = MFMA16(a[1], bfr, q1);
        #pragma unroll
        for (int r = 0; r < 4; ++r) {
            qpart[(j * 128 + wave * 32 + quad * 4 + r) * 512 + nt * 16 + col] = q0[r];
            qpart[(j * 128 + wave * 32 + 16 + quad * 4 + r) * 512 + nt * 16 + col] = q1[r];
        }
    }
}

// ---------------------------------------------------------------------------
// K_step (launch tt = 0..126), 160 blocks x 1024 thr:
//   blocks 0..31  : gates for step tt-1 (GEMM+LSTM+qGEMM only, tid<256),
//                   then 32-producer fetch_add; last arriver fans out 128
//                   private flag words.
//   blocks 32..159: attention for step tt, batch row b = blk-32.  16 waves
//                   x 32 s-rows = full 512-row softmax in-block; ctx
//                   normalized locally and written DIRECTLY to x_sw.
// No part_m/part_l/part_ctx; no duplicated combine.
// ---------------------------------------------------------------------------
__global__ __launch_bounds__(1024, 4) void k_step(
    const char* __restrict__ proj8, const f16* __restrict__ enc_out,
    float* __restrict__ qpart, const float* __restrict__ attn_bp,
    const float* __restrict__ attn_vp, const int* __restrict__ trg,
    const f16* __restrict__ dec_emb, f16* __restrict__ x_sw,
    f16* __restrict__ hdec0, f16* __restrict__ hdec1,
    const f16* __restrict__ wih_sw, const f16* __restrict__ whh_sw,
    const float* __restrict__ dec_bp, float* __restrict__ c_ws,
    f16* __restrict__ hhist_sw, const f16* __restrict__ WhT_sw,
    unsigned* __restrict__ flags, int tt)
{
    int blk = blockIdx.x;
    int tid = threadIdx.x, wave = tid >> 6, lane = tid & 63;
    int col = lane & 15, quad = lane >> 4;

    __shared__ float q[512];
    __shared__ float sc[512];
    __shared__ float ctxred[16][512];
    __shared__ float wred[16], wred2[16];
    __shared__ f16 hsl[64][40];
    __shared__ int islast;

    if (blk < 32) {
        // ============ gates phase: step tg = tt-1 (blocks 0..31) ============
        int tg = tt - 1;
        if (tg >= 0) {
            int j = blk >> 1, mh = blk & 1;
            if (tid < 256) {
                const f16* hprev = (tg & 1) ? hdec1 : hdec0;
                f16* hnext = (tg & 1) ? hdec0 : hdec1;

                f32x4 acc[8] = {};
                for (int ks = 0; ks < 36; ++ks) {
                    int mtile = mh * 4 + wave;
                    half8 a = (ks < 20)
                        ? *(const half8*)(x_sw + ((mtile * 20 + ks) * 64 + lane) * 8)
                        : *(const half8*)(hprev + ((mtile * 16 + (ks - 20)) * 64 + lane) * 8);
                    half8 bv[8];
                    #pragma unroll
                    for (int jt = 0; jt < 8; ++jt) {
                        int g = jt >> 1, u2 = jt & 1;
                        int ntile = g * 32 + j * 2 + u2;
                        bv[jt] = (ks < 20)
                            ? *(const half8*)(wih_sw + ((ntile * 20 + ks) * 64 + lane) * 8)
                            : *(const half8*)(whh_sw + ((ntile * 16 + (ks - 20)) * 64 + lane) * 8);
                    }
                    #pragma unroll
                    for (int jt = 0; jt < 8; ++jt)
                        acc[jt] = MFMA16(a, bv[jt], acc[jt]);
                }
                float bias[8];
                #pragma unroll
                for (int jt = 0; jt < 8; ++jt) {
                    int g = jt >> 1, u2 = jt & 1;
                    bias[jt] = dec_bp[g * 512 + j * 32 + u2 * 16 + col];
                }
                #pragma unroll
                for (int r = 0; r < 4; ++r) {
                    int lb = wave * 16 + quad * 4 + r;
                    int bb = mh * 64 + lb;
                    #pragma unroll
                    for (int u2 = 0; u2 < 2; ++u2) {
                        int hl = u2 * 16 + col, hcol = j * 32 + hl;
                        float gi = acc[0 + u2][r] + bias[0 + u2];
                        float gf = acc[2 + u2][r] + bias[2 + u2];
                        float gg = acc[4 + u2][r] + bias[4 + u2];
                        float go = acc[6 + u2][r] + bias[6 + u2];
                        float ig = fsig(gi), fg = fsig(gf), g2 = ftanh(gg), og = fsig(go);
                        float cv = fg * c_ws[bb * 512 + hcol] + ig * g2;
                        c_ws[bb * 512 + hcol] = cv;
                        float h = og * ftanh(cv);
                        f16 h16 = (f16)h;
                        int fidx = frag_idx(bb, hcol, 16);
                        hnext[fidx] = h16;
                        hhist_sw[tg * 65536 + fidx] = h16;
                        hsl[lb][hl] = h16;
                    }
                }
                half8 aq = *(const half8*)(&hsl[wave * 16 + col][quad * 8]);
                for (int nt = 0; nt < 32; ++nt) {
                    half8 bq = *(const half8*)(WhT_sw + ((nt * 16 + j) * 64 + lane) * 8);
                    f32x4 q0 = {};
                    q0 = MFMA16(aq, bq, q0);
                    #pragma unroll
                    for (int r = 0; r < 4; ++r)
                        qpart[(j * 128 + mh * 64 + wave * 16 + quad * 4 + r) * 512 + nt * 16 + col] = q0[r];
                }
            }

            // ---- release: arrive on counter; last arriver fans out flags ----
            __syncthreads();
            if (tid == 0) {
                unsigned old = __hip_atomic_fetch_add(flags, 1u, __ATOMIC_ACQ_REL,
                                                      __HIP_MEMORY_SCOPE_AGENT);
                islast = (old == (unsigned)(32 * tt - 1)) ? 1 : 0;
            }
            __syncthreads();
            if (islast && tid < 128)
                __hip_atomic_store(flags + 16 + tid * 16, (unsigned)tt,
                                   __ATOMIC_RELEASE, __HIP_MEMORY_SCOPE_AGENT);
        }
        return;
    }

    // ============ attention phase: step tt, batch row b (blocks 32..159) ============
    int b = blk - 32;

    float vreg[8];
    #pragma unroll
    for (int u = 0; u < 8; ++u) vreg[u] = attn_vp[lane * 8 + u];

    if (tt > 0) {
        if (tid == 0) {
            while (__hip_atomic_load(flags + 16 + b * 16, __ATOMIC_RELAXED,
                                     __HIP_MEMORY_SCOPE_AGENT) < (unsigned)tt)
                __builtin_amdgcn_s_sleep(16);
            (void)__hip_atomic_load(flags + 16 + b * 16, __ATOMIC_ACQUIRE,
                                    __HIP_MEMORY_SCOPE_AGENT);
        }
        __syncthreads();
    }

    if (tid < 512) {
        float s = attn_bp[tid];
        #pragma unroll
        for (int jj = 0; jj < 16; ++jj) s += qpart[(jj * 128 + b) * 512 + tid];
        q[tid] = s;
    }
    __syncthreads();

    float qreg[8];
    #pragma unroll
    for (int u = 0; u < 8; ++u) qreg[u] = q[lane * 8 + u];

    // scores: 16 waves x 32 rows; 8-deep batching; int8 proj decode inline
    for (int ib = 0; ib < 4; ++ib) {
        char8v p[8];
        #pragma unroll
        for (int z = 0; z < 8; ++z) {
            int sl = (ib * 8 + z) * 16 + wave;
            p[z] = *(const char8v*)(proj8 + ((size_t)b * 512 + sl) * 512 + lane * 8);
        }
        #pragma unroll
        for (int z = 0; z < 8; ++z) {
            int sl = (ib * 8 + z) * 16 + wave;
            float part = 0.f;
            #pragma unroll
            for (int u = 0; u < 8; ++u)
                part += vreg[u] * ftanh(fmaf((float)p[z][u], PSCALE, qreg[u]));
            #pragma unroll
            for (int o = 32; o; o >>= 1) part += __shfl_xor(part, o);
            if (lane == 0) sc[sl] = part;
        }
    }
    __syncthreads();

    // full-row softmax stats over 512 entries
    float s0 = (tid < 512) ? sc[tid] : -__builtin_inff();
    float mv = s0;
    #pragma unroll
    for (int o = 32; o; o >>= 1) mv = fmaxf(mv, __shfl_xor(mv, o));
    if (lane == 0) wred[wave] = mv;
    __syncthreads();
    float M = wred[0];
    #pragma unroll
    for (int w = 1; w < 16; ++w) M = fmaxf(M, wred[w]);
    float e0 = (tid < 512) ? __expf(s0 - M) : 0.f;
    if (tid < 512) sc[tid] = e0;
    float sm = e0;
    #pragma unroll
    for (int o = 32; o; o >>= 1) sm += __shfl_xor(sm, o);
    if (lane == 0) wred2[wave] = sm;
    __syncthreads();
    float lsum = wred2[0];
    #pragma unroll
    for (int w = 1; w < 16; ++w) lsum += wred2[w];

    // ctx: same 32 rows per wave; 8-deep half8 batching
    float a8[8] = {};
    for (int ib = 0; ib < 4; ++ib) {
        half8 ev[8];
        float wgt[8];
        #pragma unroll
        for (int z = 0; z < 8; ++z) {
            int sl = (ib * 8 + z) * 16 + wave;
            ev[z] = *(const half8*)(enc_out + ((size_t)b * 512 + sl) * 512 + lane * 8);
            wgt[z] = sc[sl];
        }
        #pragma unroll
        for (int z = 0; z < 8; ++z)
            #pragma unroll
            for (int u = 0; u < 8; ++u) a8[u] += wgt[z] * (float)ev[z][u];
    }
    #pragma unroll
    for (int u = 0; u < 8; ++u) ctxred[wave][lane * 8 + u] = a8[u];
    __syncthreads();
    if (tid < 512) {
        float cp = 0.f;
        #pragma unroll
        for (int w = 0; w < 16; ++w) cp += ctxred[w][tid];
        x_sw[frag_idx(b, 128 + tid, 20)] = (f16)(cp * (1.f / lsum));
    }
    if (tid < 128) {
        int tok = trg[b * 128 + tt];
        x_sw[frag_idx(b, tid, 20)] = dec_emb[tok * 128 + tid];
    }
}

// ---------------------------------------------------------------------------
// K_gates_fin: gates for the final step (t=126); no prologue, no q-GEMM.
// ---------------------------------------------------------------------------
__global__ __launch_bounds__(256) void k_gates_fin(
    const f16* __restrict__ x_sw, const f16* __restrict__ hprev_sw,
    const f16* __restrict__ wih_sw, const f16* __restrict__ whh_sw,
    const float* __restrict__ dec_b, float* __restrict__ c_ws,
    f16* __restrict__ hhist_sw, int t)
{
    int jb = blockIdx.x;
    int j = jb >> 1, mh = jb & 1;
    int tid = threadIdx.x, wave = tid >> 6, lane = tid & 63;
    int col = lane & 15, quad = lane >> 4;

    f32x4 acc[8] = {};
    for (int ks = 0; ks < 36; ++ks) {
        int mtile = mh * 4 + wave;
        half8 a = (ks < 20)
            ? *(const half8*)(x_sw + ((mtile * 20 + ks) * 64 + lane) * 8)
            : *(const half8*)(hprev_sw + ((mtile * 16 + (ks - 20)) * 64 + lane) * 8);
        half8 bv[8];
        #pragma unroll
        for (int jt = 0; jt < 8; ++jt) {
            int g = jt >> 1, u2 = jt & 1;
            int ntile = g * 32 + j * 2 + u2;
            bv[jt] = (ks < 20)
                ? *(const half8*)(wih_sw + ((ntile * 20 + ks) * 64 + lane) * 8)
                : *(const half8*)(whh_sw + ((ntile * 16 + (ks - 20)) * 64 + lane) * 8);
        }
        #pragma unroll
        for (int jt = 0; jt < 8; ++jt)
            acc[jt] = MFMA16(a, bv[jt], acc[jt]);
    }
    float bias[8];
    #pragma unroll
    for (int jt = 0; jt < 8; ++jt) {
        int g = jt >> 1, u2 = jt & 1;
        bias[jt] = dec_b[g * 512 + j * 32 + u2 * 16 + col];
    }
    #pragma unroll
    for (int r = 0; r < 4; ++r) {
        int lb = wave * 16 + quad * 4 + r;
        int bb = mh * 64 + lb;
        #pragma unroll
        for (int u2 = 0; u2 < 2; ++u2) {
            int hl = u2 * 16 + col, hcol = j * 32 + hl;
            float gi = acc[0 + u2][r] + bias[0 + u2];
            float gf = acc[2 + u2][r] + bias[2 + u2];
            float gg = acc[4 + u2][r] + bias[4 + u2];
            float go = acc[6 + u2][r] + bias[6 + u2];
            float ig = fsig(gi), fg = fsig(gf), g2 = ftanh(gg), og = fsig(go);
            float cv = fg * c_ws[bb * 512 + hcol] + ig * g2;
            c_ws[bb * 512 + hcol] = cv;
            float h = og * ftanh(cv);
            hhist_sw[t * 65536 + frag_idx(bb, hcol, 16)] = (f16)h;
        }
    }
}

// ---------------------------------------------------------------------------
// K_logits: batched over all 127 steps (once).
// ---------------------------------------------------------------------------
__global__ __launch_bounds__(256) void k_logits(
    const f16* __restrict__ hhist_sw, const f16* __restrict__ outWT_sw,
    const float* __restrict__ out_b, float* __restrict__ out)
{
    int bt = blockIdx.x;
    int tid = threadIdx.x, wave = tid >> 6, lane = tid & 63;
    int col = lane & 15, quad = lane >> 4;
    f32x4 acc[2][8] = {};
    for (int ks = 0; ks < 16; ++ks) {
        half8 a[2];
        #pragma unroll
        for (int i = 0; i < 2; ++i)
            a[i] = *(const half8*)(hhist_sw + bt * 65536 + (((wave * 2 + i) * 16 + ks) * 64 + lane) * 8);
        half8 bv[8];
        #pragma unroll
        for (int jt = 0; jt < 8; ++jt)
            bv[jt] = *(const half8*)(outWT_sw + ((jt * 16 + ks) * 64 + lane) * 8);
        #pragma unroll
        for (int jt = 0; jt < 8; ++jt) {
            acc[0][jt] = MFMA16(a[0], bv[jt], acc[0][jt]);
            acc[1][jt] = MFMA16(a[1], bv[jt], acc[1][jt]);
        }
    }
    #pragma unroll
    for (int jt = 0; jt < 8; ++jt) {
        float bias = out_b[jt * 16 + col];
        #pragma unroll
        for (int i = 0; i < 2; ++i)
            #pragma unroll
            for (int r = 0; r < 4; ++r) {
                int br = wave * 32 + i * 16 + quad * 4 + r;
                out[br * 16384 + (bt + 1) * 128 + jt * 16 + col] = acc[i][jt][r] + bias;
            }
    }
}

// ---------------------------------------------------------------------------
extern "C" void kernel_launch(void* const* d_in, const int* in_sizes, int n_in,
                              void* d_out, int out_size, void* d_ws, size_t ws_size,
                              hipStream_t stream)
{
    (void)in_sizes; (void)n_in; (void)out_size;
    if (ws_size < 130000000) return;  // clean bail if workspace too small

    const int*   src     = (const int*)d_in[0];
    const int*   trg     = (const int*)d_in[1];
    const float* enc_emb = (const float*)d_in[2];
    const float* wihf    = (const float*)d_in[3];
    const float* whhf    = (const float*)d_in[4];
    const float* bf_     = (const float*)d_in[5];
    const float* wihb    = (const float*)d_in[6];
    const float* whhb    = (const float*)d_in[7];
    const float* bb_     = (const float*)d_in[8];
    const float* dec_emb = (const float*)d_in[9];
    const float* dec_wih = (const float*)d_in[10];
    const float* dec_whh = (const float*)d_in[11];
    const float* dec_b   = (const float*)d_in[12];
    const float* attn_W  = (const float*)d_in[13];
    const float* attn_b  = (const float*)d_in[14];
    const float* attn_v  = (const float*)d_in[15];
    const float* out_W   = (const float*)d_in[16];
    const float* out_b   = (const float*)d_in[17];
    float* out = (float*)d_out;

    char* p = (char*)d_ws;
    auto carve = [&](size_t n) { char* r = p; p += ((n + 255) & ~(size_t)255); return r; };
    f16*   enc_out   = (f16*)  carve(67108864);
    char*  proj8     = (char*) carve(33554432);   // 65536 x 512 int8
    f16*   WhT_sw    = (f16*)  carve(524288);
    f16*   WeT       = (f16*)  carve(524288);
    f16*   outWT_sw  = (f16*)  carve(131072);
    f16*   emb16     = (f16*)  carve(32768);
    f16*   wihf16    = (f16*)  carve(262144);
    f16*   wihb16    = (f16*)  carve(262144);
    f16*   whhf_sw   = (f16*)  carve(524288);
    f16*   whhb_sw   = (f16*)  carve(524288);
    f16*   decemb16  = (f16*)  carve(32768);
    f16*   decwih_sw = (f16*)  carve(2621440);
    f16*   decwhh_sw = (f16*)  carve(2097152);
    float* qpart     = (float*)carve(4194304);
    f16*   hdec0     = (f16*)  carve(131072);
    f16*   hdec1     = (f16*)  carve(131072);
    float* c_ws      = (float*)carve(262144);
    f16*   x_sw      = (f16*)  carve(163840);
    f16*   hhist_sw  = (f16*)  carve(16646144);
    f16*   xg_vocab  = (f16*)  carve(524288);
    unsigned* flagsv = (unsigned*)carve(16448);   // counter + 128 private lines

    k_zero<<<1, 256, 0, stream>>>(flagsv);
    k_prep<<<14784, 256, 0, stream>>>(attn_W, out_W, enc_emb, wihf, wihb, whhf, whhb,
                                      dec_emb, dec_wih, dec_whh,
                                      WhT_sw, outWT_sw, whhf_sw, whhb_sw,
                                      decwih_sw, decwhh_sw, WeT, emb16,
                                      wihf16, wihb16, decemb16, out);
    k_vocab<<<16, 256, 0, stream>>>(emb16, wihf16, wihb16, bf_, bb_, xg_vocab);
    k_enc<<<16, 512, 0, stream>>>(src, xg_vocab, whhf_sw, whhb_sw, enc_out, hdec0, c_ws);
    k_proj<<<2048, 256, 0, stream>>>(enc_out, WeT, proj8);
    k_qinit<<<16, 256, 0, stream>>>(hdec0, WhT_sw, qpart);

    // decode: one launch per step (gates for t-1 fused ahead of attention t)
    for (int tt = 0; tt < 127; ++tt)
        k_step<<<160, 1024, 0, stream>>>(proj8, enc_out, qpart, attn_b, attn_v,
                                         trg, decemb16, x_sw, hdec0, hdec1,
                                         decwih_sw, decwhh_sw, dec_b, c_ws,
                                         hhist_sw, WhT_sw, flagsv, tt);
    // trailing gates for the last step (t=126): hprev = hdec0 (126 even)
    k_gates_fin<<<32, 256, 0, stream>>>(x_sw, hdec0, decwih_sw, decwhh_sw,
                                        dec_b, c_ws, hhist_sw, 126);

    k_logits<<<127, 256, 0, stream>>>(hhist_sw, outWT_sw, out_b, out);
}

// Round 7
// 12515.253 us; speedup vs baseline: 1.0303x; 1.0303x over previous
//
#include <hip/hip_runtime.h>

// ============================================================================
// Seq2Seq (bi-LSTM encoder + Bahdanau-attention LSTM decoder) on gfx950.
// fp32 in/out; fp16 internal (fp32 accum/state).
// R18 = R16 (12.46 ms, best) + decentralized gates->att sync:
//   R17 (full-row attention) regressed -> decode body reverted to R16's
//   288x512 k_step with softmax partials.  R16's flag path audited: a
//   single fetch_add ACQ_REL cacheline serializes 32 cross-XCD RMWs
//   (~400-600cy each) + a fan-out stage behind it (~8 us/step total).
//   Fix: each gates block release-stores its OWN 64B-spaced flag word
//   (32 concurrent releases); consumers sweep-poll all 32 words with one
//   wave-instr (lanes 0..31 + __ballot) and a single ACQUIRE on exit.
//   Attention prefetches its ib=0 proj8 rows before polling.
// k_enc unchanged from R16 (3.51 ms).
// ============================================================================

typedef _Float16 f16;
typedef _Float16 half8 __attribute__((ext_vector_type(8)));
typedef float f32x4 __attribute__((ext_vector_type(4)));
typedef char char8v __attribute__((ext_vector_type(8)));

#define MFMA16(a, b, c) __builtin_amdgcn_mfma_f32_16x16x32_f16((a), (b), (c), 0, 0, 0)

#define PSCALE (2.5f / 127.f)      // int8 proj dequant scale
#define PINV   (127.f / 2.5f)      // quant scale

__device__ __forceinline__ float fsig(float x) {
    return __builtin_amdgcn_rcpf(1.f + __expf(-x));
}
__device__ __forceinline__ float ftanh(float x) {
    return 1.f - 2.f * __builtin_amdgcn_rcpf(1.f + __expf(2.f * x));
}
__device__ __forceinline__ int frag_idx(int m, int k, int KS) {
    return (((m >> 4) * KS + (k >> 5)) * 64 + (((k >> 3) & 3) * 16 + (m & 15))) * 8 + (k & 7);
}

// LDS-only barrier: waits own-wave LDS ops, then barrier.  Deliberately does
// NOT drain vmcnt -- global stores/prefetches stay in flight across steps.
__device__ __forceinline__ void lds_barrier() {
    asm volatile("s_waitcnt lgkmcnt(0)" ::: "memory");
    __builtin_amdgcn_sched_barrier(0);
    __builtin_amdgcn_s_barrier();
    __builtin_amdgcn_sched_barrier(0);
}

// ---------------------------------------------------------------------------
// K_zero: reset flag region (each graph replay).
// flags[i*16] = done-step word for gates block i (i < 32), 64B spacing.
// ---------------------------------------------------------------------------
__global__ void k_zero(unsigned* __restrict__ s)
{
    for (int z = threadIdx.x; z < 4112; z += 256) s[z] = 0u;
}

// ---------------------------------------------------------------------------
// K0: one-shot: pack weights to fragment order (f32 -> f16), plain converts,
// zero out t=0 output row.
// ---------------------------------------------------------------------------
__global__ __launch_bounds__(256) void k_prep(
    const float* __restrict__ attn_W, const float* __restrict__ out_W,
    const float* __restrict__ enc_emb,
    const float* __restrict__ wihf, const float* __restrict__ wihb,
    const float* __restrict__ whhf, const float* __restrict__ whhb,
    const float* __restrict__ dec_emb, const float* __restrict__ dec_wih,
    const float* __restrict__ dec_whh,
    f16* __restrict__ WhT_sw, f16* __restrict__ outWT_sw,
    f16* __restrict__ whhf_sw, f16* __restrict__ whhb_sw,
    f16* __restrict__ decwih_sw, f16* __restrict__ decwhh_sw,
    f16* __restrict__ WeT, f16* __restrict__ emb16,
    f16* __restrict__ wihf16, f16* __restrict__ wihb16,
    f16* __restrict__ decemb16, float* __restrict__ out)
{
    long i = (long)blockIdx.x * 256 + threadIdx.x;
    if (i >= 3784704L) return;
    long idx = i;
    if (idx < 262144) {  // WhT_sw: N=512(e) x K=512(d)
        int j = idx & 7, lane = (idx >> 3) & 63, c = lane & 15, q = lane >> 4;
        int ks = (idx >> 9) & 15, nt = idx >> 13;
        WhT_sw[idx] = (f16)attn_W[(ks * 32 + q * 8 + j) * 512 + nt * 16 + c];
        return;
    }
    idx -= 262144;
    if (idx < 65536) {   // outWT_sw: N=128(v) x K=512(d)
        int j = idx & 7, lane = (idx >> 3) & 63, c = lane & 15, q = lane >> 4;
        int ks = (idx >> 9) & 15, nt = idx >> 13;
        outWT_sw[idx] = (f16)out_W[(ks * 32 + q * 8 + j) * 128 + nt * 16 + c];
        return;
    }
    idx -= 65536;
    if (idx < 262144) {  // whhf_sw: N=1024 x K=256
        int j = idx & 7, lane = (idx >> 3) & 63, c = lane & 15, q = lane >> 4;
        int ks = (idx >> 9) & 7, nt = idx >> 12;
        whhf_sw[idx] = (f16)whhf[(nt * 16 + c) * 256 + ks * 32 + q * 8 + j];
        return;
    }
    idx -= 262144;
    if (idx < 262144) {  // whhb_sw
        int j = idx & 7, lane = (idx >> 3) & 63, c = lane & 15, q = lane >> 4;
        int ks = (idx >> 9) & 7, nt = idx >> 12;
        whhb_sw[idx] = (f16)whhb[(nt * 16 + c) * 256 + ks * 32 + q * 8 + j];
        return;
    }
    idx -= 262144;
    if (idx < 1310720) { // decwih_sw: N=2048 x K=640
        int j = idx & 7, lane = (idx >> 3) & 63, c = lane & 15, q = lane >> 4;
        int r2 = idx >> 9; int ks = r2 % 20, nt = r2 / 20;
        decwih_sw[idx] = (f16)dec_wih[(nt * 16 + c) * 640 + ks * 32 + q * 8 + j];
        return;
    }
    idx -= 1310720;
    if (idx < 1048576) { // decwhh_sw: N=2048 x K=512
        int j = idx & 7, lane = (idx >> 3) & 63, c = lane & 15, q = lane >> 4;
        int ks = (idx >> 9) & 15, nt = idx >> 13;
        decwhh_sw[idx] = (f16)dec_whh[(nt * 16 + c) * 512 + ks * 32 + q * 8 + j];
        return;
    }
    idx -= 1048576;
    if (idx < 262144) { int e = idx >> 9, d = idx & 511; WeT[idx] = (f16)attn_W[(512 + d) * 512 + e]; return; }
    idx -= 262144;
    if (idx < 16384)  { emb16[idx] = (f16)enc_emb[idx]; return; }
    idx -= 16384;
    if (idx < 131072) { wihf16[idx] = (f16)wihf[idx]; return; }
    idx -= 131072;
    if (idx < 131072) { wihb16[idx] = (f16)wihb[idx]; return; }
    idx -= 131072;
    if (idx < 16384)  { decemb16[idx] = (f16)dec_emb[idx]; return; }
    idx -= 16384;
    if (idx < 16384)  { int b = idx >> 7, v = idx & 127; out[b * 16384 + v] = 0.f; return; }
}

// ---------------------------------------------------------------------------
// K_vocab: xg_vocab[v][n] = emb[v] @ [Wih_f|Wih_b]^T + [b_f|b_b] (once).
// ---------------------------------------------------------------------------
__global__ __launch_bounds__(256) void k_vocab(
    const f16* __restrict__ emb, const f16* __restrict__ wihf,
    const f16* __restrict__ wihb, const float* __restrict__ bf_,
    const float* __restrict__ bb_, f16* __restrict__ xg_vocab)
{
    int bn = blockIdx.x;
    int tid = threadIdx.x, wave = tid >> 6, lane = tid & 63;
    int col = lane & 15, quad = lane >> 4;
    int wr = wave >> 1, wc = wave & 1;

    f32x4 acc[4][4] = {};
    for (int ks = 0; ks < 4; ++ks) {
        int k0 = ks * 32 + quad * 8;
        half8 a[4], bfr[4];
        for (int i = 0; i < 4; ++i)
            a[i] = *(const half8*)(emb + (wr * 64 + i * 16 + col) * 128 + k0);
        for (int j = 0; j < 4; ++j) {
            int n = bn * 128 + wc * 64 + j * 16 + col;
            const f16* wp = (n < 1024) ? (wihf + n * 128) : (wihb + (n - 1024) * 128);
            bfr[j] = *(const half8*)(wp + k0);
        }
        for (int i = 0; i < 4; ++i)
            for (int j = 0; j < 4; ++j)
                acc[i][j] = MFMA16(a[i], bfr[j], acc[i][j]);
    }
    for (int j = 0; j < 4; ++j) {
        int n = bn * 128 + wc * 64 + j * 16 + col;
        float bias = (n < 1024) ? bf_[n] : bb_[n - 1024];
        for (int i = 0; i < 4; ++i) {
            int vbase = wr * 64 + i * 16 + quad * 4;
            for (int r = 0; r < 4; ++r)
                xg_vocab[(vbase + r) * 2048 + n] = (f16)(acc[i][j][r] + bias);
        }
    }
}

// ---------------------------------------------------------------------------
// K_enc (R16 form): encoder scan, 16 blocks, 512 threads, one lgkm-only
// barrier per t-step; hb/xvb double-buffered; no vmcnt drain in-loop.
// ---------------------------------------------------------------------------
__global__ __launch_bounds__(512, 1) void k_enc(
    const int* __restrict__ src, const f16* __restrict__ xg_vocab,
    const f16* __restrict__ whhf_sw, const f16* __restrict__ whhb_sw,
    f16* __restrict__ enc_out, f16* __restrict__ hdec0, float* __restrict__ c_ws)
{
    int blk = blockIdx.x;
    int dir = blk >> 3, bbase = (blk & 7) * 16;
    int tid = threadIdx.x, wave = tid >> 6, lane = tid & 63;
    int col = lane & 15, quad = lane >> 4;
    const f16* whh = dir ? whhb_sw : whhf_sw;

    __shared__ f16 hb[2][16][264];
    __shared__ f16 xvb[2][16][1032];
    __shared__ unsigned short stall[8192];   // [b][t] tokens (VIN=128 fits u16)

    for (int z = tid; z < 2 * 16 * 264; z += 512) ((f16*)hb)[z] = (f16)0.f;
    for (int z = tid; z < 8192; z += 512) stall[z] = (unsigned short)src[bbase * 512 + z];
    float cc[2][4] = {};

    // gate-0 Whh fragments resident in VGPRs: 16 half8 = 64 VGPR
    half8 bst[16];
    #pragma unroll
    for (int nt = 0; nt < 2; ++nt)
        #pragma unroll
        for (int kk = 0; kk < 8; ++kk) {
            int tile = wave * 2 + nt;
            bst[nt * 8 + kk] = *(const half8*)(whh + ((tile * 8 + kk) * 64 + lane) * 8);
        }
    __syncthreads();

    int xrow = tid >> 7, xoff = (tid & 127) * 8;
    half8 xr[4];
    {
        int ts0 = dir ? 511 : 0;
        #pragma unroll
        for (int it = 0; it < 4; ++it) {
            int row = it * 4 + xrow;
            int tok = stall[row * 512 + ts0];
            xr[it] = *(const half8*)(xg_vocab + tok * 2048 + dir * 1024 + xoff);
        }
        #pragma unroll
        for (int it = 0; it < 4; ++it)
            *(half8*)(&xvb[0][it * 4 + xrow][xoff]) = xr[it];
    }
    __syncthreads();

    int ts_prev = 0;
    for (int t = 0; t < 512; ++t) {
        int ts = dir ? (511 - t) : t;
        int cur = t & 1, prv = cur ^ 1;

        if (t < 511) {
            int tsn = dir ? (510 - t) : (t + 1);
            #pragma unroll
            for (int it = 0; it < 4; ++it) {
                int row = it * 4 + xrow;
                int tok = stall[row * 512 + tsn];
                xr[it] = *(const half8*)(xg_vocab + tok * 2048 + dir * 1024 + xoff);
            }
        }

        if (t > 0) {
            int b = tid >> 5, seg = tid & 31;
            *(half8*)(enc_out + ((size_t)(bbase + b) * 512 + ts_prev) * 512 + dir * 256 + seg * 8) =
                *(const half8*)(&hb[prv][b][seg * 8]);
        }

        half8 a[8];
        #pragma unroll
        for (int kk = 0; kk < 8; ++kk)
            a[kk] = *(const half8*)(&hb[prv][col][kk * 32 + quad * 8]);

        f32x4 acc[4][2] = {};
        #pragma unroll
        for (int kk = 0; kk < 8; ++kk) {
            half8 bv[6];
            #pragma unroll
            for (int g = 1; g < 4; ++g)
                #pragma unroll
                for (int nt = 0; nt < 2; ++nt) {
                    int tile = g * 16 + wave * 2 + nt;
                    bv[(g - 1) * 2 + nt] =
                        *(const half8*)(whh + ((tile * 8 + kk) * 64 + lane) * 8);
                }
            #pragma unroll
            for (int nt = 0; nt < 2; ++nt)
                acc[0][nt] = MFMA16(a[kk], bst[nt * 8 + kk], acc[0][nt]);
            #pragma unroll
            for (int g = 1; g < 4; ++g)
                #pragma unroll
                for (int nt = 0; nt < 2; ++nt)
                    acc[g][nt] = MFMA16(a[kk], bv[(g - 1) * 2 + nt], acc[g][nt]);
        }

        #pragma unroll
        for (int nt = 0; nt < 2; ++nt) {
            int hcol = wave * 32 + nt * 16 + col;
            #pragma unroll
            for (int r = 0; r < 4; ++r) {
                int b = quad * 4 + r;
                float gi = (float)xvb[cur][b][0 * 256 + hcol] + acc[0][nt][r];
                float gf = (float)xvb[cur][b][1 * 256 + hcol] + acc[1][nt][r];
                float gg = (float)xvb[cur][b][2 * 256 + hcol] + acc[2][nt][r];
                float go = (float)xvb[cur][b][3 * 256 + hcol] + acc[3][nt][r];
                float ig = fsig(gi), fg = fsig(gf), g2 = ftanh(gg), og = fsig(go);
                float cv = fg * cc[nt][r] + ig * g2;
                cc[nt][r] = cv;
                float h = og * ftanh(cv);
                hb[cur][b][hcol] = (f16)h;
            }
        }

        if (t < 511) {
            #pragma unroll
            for (int it = 0; it < 4; ++it)
                *(half8*)(&xvb[prv][it * 4 + xrow][xoff]) = xr[it];
        }

        lds_barrier();
        ts_prev = ts;
    }

    {
        int b = tid >> 5, seg = tid & 31;
        *(half8*)(enc_out + ((size_t)(bbase + b) * 512 + ts_prev) * 512 + dir * 256 + seg * 8) =
            *(const half8*)(&hb[1][b][seg * 8]);
    }
    #pragma unroll
    for (int nt = 0; nt < 2; ++nt) {
        int hcol = wave * 32 + nt * 16 + col;
        #pragma unroll
        for (int r = 0; r < 4; ++r) {
            int b = quad * 4 + r;
            int m = bbase + b, k = dir * 256 + hcol;
            hdec0[frag_idx(m, k, 16)] = hb[1][b][hcol];
            c_ws[m * 512 + k] = cc[nt][r];
        }
    }
}

// ---------------------------------------------------------------------------
// K_proj: enc_proj = enc_out @ We (once).  Writes int8 (fixed scale).
// ---------------------------------------------------------------------------
__global__ __launch_bounds__(256) void k_proj(
    const f16* __restrict__ enc_out, const f16* __restrict__ WeT,
    char* __restrict__ proj8)
{
    int blk = blockIdx.x;
    int bm = blk & 511, bn = blk >> 9;
    int tid = threadIdx.x, wave = tid >> 6, lane = tid & 63;
    int col = lane & 15, quad = lane >> 4;
    int wr = wave >> 1, wc = wave & 1;

    f32x4 acc[4][4] = {};
    for (int ks = 0; ks < 16; ++ks) {
        int k0 = ks * 32 + quad * 8;
        half8 a[4], bfr[4];
        for (int i = 0; i < 4; ++i) {
            int m = bm * 128 + wr * 64 + i * 16 + col;
            a[i] = *(const half8*)(enc_out + (size_t)m * 512 + k0);
        }
        for (int j = 0; j < 4; ++j) {
            int n = bn * 128 + wc * 64 + j * 16 + col;
            bfr[j] = *(const half8*)(WeT + n * 512 + k0);
        }
        for (int i = 0; i < 4; ++i)
            for (int j = 0; j < 4; ++j)
                acc[i][j] = MFMA16(a[i], bfr[j], acc[i][j]);
    }
    for (int j = 0; j < 4; ++j) {
        int n = bn * 128 + wc * 64 + j * 16 + col;
        for (int i = 0; i < 4; ++i) {
            int mbase = bm * 128 + wr * 64 + i * 16 + quad * 4;
            for (int r = 0; r < 4; ++r) {
                float v = acc[i][j][r] * PINV;
                int q = (int)rintf(v);
                q = (q > 127) ? 127 : ((q < -127) ? -127 : q);
                proj8[(size_t)(mbase + r) * 512 + n] = (char)q;
            }
        }
    }
}

// ---------------------------------------------------------------------------
// K_qinit: initial q-partials (once).
// ---------------------------------------------------------------------------
__global__ __launch_bounds__(256) void k_qinit(
    const f16* __restrict__ h0_sw, const f16* __restrict__ WhT_sw,
    float* __restrict__ qpart)
{
    int j = blockIdx.x;
    int tid = threadIdx.x, wave = tid >> 6, lane = tid & 63;
    int col = lane & 15, quad = lane >> 4;
    half8 a[2];
    #pragma unroll
    for (int i = 0; i < 2; ++i)
        a[i] = *(const half8*)(h0_sw + (((wave * 2 + i) * 16 + j) * 64 + lane) * 8);
    for (int nt = 0; nt < 32; ++nt) {
        half8 bfr = *(const half8*)(WhT_sw + ((nt * 16 + j) * 64 + lane) * 8);
        f32x4 q0 = {}, q1 = {};
        q0 = MFMA16(a[0], bfr, q0);
        q1 = MFMA16(a[1], bfr, q1);
        #pragma unroll
        for (int r = 0; r < 4; ++r) {
            qpart[(j * 128 + wave * 32 + quad * 4 + r) * 512 + nt * 16 + col] = q0[r];
            qpart[(j * 128 + wave * 32 + 16 + quad * 4 + r) * 512 + nt * 16 + col] = q1[r];
        }
    }
}

// ---------------------------------------------------------------------------
// K_step (launch tt = 0..126): blocks 0..31 run the LSTM-gates phase for
// step tt-1 (skipped at tt=0), each releasing its OWN flag word; blocks
// 32..287 run the attention phase for step tt after a parallel sweep-poll
// of all 32 producer words.  att->gates dependency rides the launch
// boundary.  Phase bodies verbatim R16.
// ---------------------------------------------------------------------------
__global__ __launch_bounds__(512, 4) void k_step(
    const char* __restrict__ proj8, const f16* __restrict__ enc_out,
    float* __restrict__ qpart, const float* __restrict__ attn_bp,
    const float* __restrict__ attn_vp, const int* __restrict__ trg,
    const f16* __restrict__ dec_emb, f16* __restrict__ x_sw,
    float* __restrict__ part_m, float* __restrict__ part_l,
    float* __restrict__ part_ctx, f16* __restrict__ hdec0,
    f16* __restrict__ hdec1, const f16* __restrict__ wih_sw,
    const f16* __restrict__ whh_sw, const float* __restrict__ dec_bp,
    float* __restrict__ c_ws, f16* __restrict__ hhist_sw,
    const f16* __restrict__ WhT_sw, unsigned* __restrict__ flags, int tt)
{
    int blk = blockIdx.x;
    int tid = threadIdx.x, wave = tid >> 6, lane = tid & 63;
    int col = lane & 15, quad = lane >> 4;

    __shared__ float q[512];
    __shared__ float sc[256];
    __shared__ float ctxred[8][512];
    __shared__ float wred[8], wred2[8];
    __shared__ f16 hsl[64][40];
    __shared__ float gm[64][2];

    if (blk < 32) {
        // ============ gates phase: step tg = tt-1 (blocks 0..31) ============
        int tg = tt - 1;
        if (tg >= 0) {
            int j = blk >> 1, mh = blk & 1;
            if (tid < 64) {
                int bb = mh * 64 + tid;
                float m0 = part_m[bb * 2 + 0], m1 = part_m[bb * 2 + 1];
                float l0 = part_l[bb * 2 + 0], l1 = part_l[bb * 2 + 1];
                float M = fmaxf(m0, m1);
                float g0 = __expf(m0 - M), g1 = __expf(m1 - M);
                float inv = 1.f / (g0 * l0 + g1 * l1);
                gm[tid][0] = g0 * inv;
                gm[tid][1] = g1 * inv;
            }
            __syncthreads();
            for (int z = tid; z < 32768; z += 512) {
                int lr = z >> 9, d = z & 511;
                int bb = mh * 64 + lr;
                float c = gm[lr][0] * part_ctx[(size_t)(bb * 2 + 0) * 512 + d]
                        + gm[lr][1] * part_ctx[(size_t)(bb * 2 + 1) * 512 + d];
                x_sw[frag_idx(bb, 128 + d, 20)] = (f16)c;
            }
            __syncthreads();

            if (tid < 256) {
                const f16* hprev = (tg & 1) ? hdec1 : hdec0;
                f16* hnext = (tg & 1) ? hdec0 : hdec1;

                f32x4 acc[8] = {};
                for (int ks = 0; ks < 36; ++ks) {
                    int mtile = mh * 4 + wave;
                    half8 a = (ks < 20)
                        ? *(const half8*)(x_sw + ((mtile * 20 + ks) * 64 + lane) * 8)
                        : *(const half8*)(hprev + ((mtile * 16 + (ks - 20)) * 64 + lane) * 8);
                    half8 bv[8];
                    #pragma unroll
                    for (int jt = 0; jt < 8; ++jt) {
                        int g = jt >> 1, u2 = jt & 1;
                        int ntile = g * 32 + j * 2 + u2;
                        bv[jt] = (ks < 20)
                            ? *(const half8*)(wih_sw + ((ntile * 20 + ks) * 64 + lane) * 8)
                            : *(const half8*)(whh_sw + ((ntile * 16 + (ks - 20)) * 64 + lane) * 8);
                    }
                    #pragma unroll
                    for (int jt = 0; jt < 8; ++jt)
                        acc[jt] = MFMA16(a, bv[jt], acc[jt]);
                }
                float bias[8];
                #pragma unroll
                for (int jt = 0; jt < 8; ++jt) {
                    int g = jt >> 1, u2 = jt & 1;
                    bias[jt] = dec_bp[g * 512 + j * 32 + u2 * 16 + col];
                }
                #pragma unroll
                for (int r = 0; r < 4; ++r) {
                    int lb = wave * 16 + quad * 4 + r;
                    int bb = mh * 64 + lb;
                    #pragma unroll
                    for (int u2 = 0; u2 < 2; ++u2) {
                        int hl = u2 * 16 + col, hcol = j * 32 + hl;
                        float gi = acc[0 + u2][r] + bias[0 + u2];
                        float gf = acc[2 + u2][r] + bias[2 + u2];
                        float gg = acc[4 + u2][r] + bias[4 + u2];
                        float go = acc[6 + u2][r] + bias[6 + u2];
                        float ig = fsig(gi), fg = fsig(gf), g2 = ftanh(gg), og = fsig(go);
                        float cv = fg * c_ws[bb * 512 + hcol] + ig * g2;
                        c_ws[bb * 512 + hcol] = cv;
                        float h = og * ftanh(cv);
                        f16 h16 = (f16)h;
                        int fidx = frag_idx(bb, hcol, 16);
                        hnext[fidx] = h16;
                        hhist_sw[tg * 65536 + fidx] = h16;
                        hsl[lb][hl] = h16;
                    }
                }
                half8 aq = *(const half8*)(&hsl[wave * 16 + col][quad * 8]);
                for (int nt = 0; nt < 32; ++nt) {
                    half8 bq = *(const half8*)(WhT_sw + ((nt * 16 + j) * 64 + lane) * 8);
                    f32x4 q0 = {};
                    q0 = MFMA16(aq, bq, q0);
                    #pragma unroll
                    for (int r = 0; r < 4; ++r)
                        qpart[(j * 128 + mh * 64 + wave * 16 + quad * 4 + r) * 512 + nt * 16 + col] = q0[r];
                }
            }

            // ---- release: this block's own flag word (no shared counter) ----
            // __syncthreads drains each wave's vmcnt, so all block stores are
            // in L2 before the release (which writes back this XCD's L2).
            __syncthreads();
            if (tid == 0)
                __hip_atomic_store(flags + blk * 16, (unsigned)tt,
                                   __ATOMIC_RELEASE, __HIP_MEMORY_SCOPE_AGENT);
        }
        return;
    }

    // ================= attention phase: step tt (blocks 32..287) =================
    int ab = blk - 32;
    int b = ab >> 1, sh = ab & 1;
    int sbase = sh * 256;

    float vreg[8];
    #pragma unroll
    for (int u = 0; u < 8; ++u) vreg[u] = attn_vp[lane * 8 + u];
    float abias = attn_bp[tid];

    // prefetch ib=0 proj8 rows (flag-independent) while producers finish
    char8v p0[8];
    #pragma unroll
    for (int z = 0; z < 8; ++z) {
        int sl = z * 8 + wave;
        p0[z] = *(const char8v*)(proj8 + ((size_t)b * 512 + sbase + sl) * 512 + lane * 8);
    }

    if (tt > 0) {
        // sweep-poll all 32 producer words in one wave-instr (lanes 0..31)
        if (wave == 0) {
            for (;;) {
                unsigned v = (lane < 32)
                    ? __hip_atomic_load(flags + lane * 16, __ATOMIC_RELAXED,
                                        __HIP_MEMORY_SCOPE_AGENT)
                    : (unsigned)tt;
                if (__ballot(v >= (unsigned)tt) == ~0ull) break;
                __builtin_amdgcn_s_sleep(8);
            }
            if (lane == 0)
                (void)__hip_atomic_load(flags, __ATOMIC_ACQUIRE,
                                        __HIP_MEMORY_SCOPE_AGENT);
        }
        __syncthreads();
    }

    {
        float s = abias;
        #pragma unroll
        for (int jj = 0; jj < 16; ++jj) s += qpart[(jj * 128 + b) * 512 + tid];
        q[tid] = s;
    }
    __syncthreads();

    float qreg[8];
    #pragma unroll
    for (int u = 0; u < 8; ++u) qreg[u] = q[lane * 8 + u];

    // scores ib=0 from the prefetched registers
    #pragma unroll
    for (int z = 0; z < 8; ++z) {
        int sl = z * 8 + wave;
        float part = 0.f;
        #pragma unroll
        for (int u = 0; u < 8; ++u)
            part += vreg[u] * ftanh(fmaf((float)p0[z][u], PSCALE, qreg[u]));
        #pragma unroll
        for (int o = 32; o; o >>= 1) part += __shfl_xor(part, o);
        if (lane == 0) sc[sl] = part;
    }
    // scores ib=1..3
    for (int ib = 1; ib < 4; ++ib) {
        char8v p[8];
        #pragma unroll
        for (int z = 0; z < 8; ++z) {
            int sl = (ib * 8 + z) * 8 + wave;
            p[z] = *(const char8v*)(proj8 + ((size_t)b * 512 + sbase + sl) * 512 + lane * 8);
        }
        #pragma unroll
        for (int z = 0; z < 8; ++z) {
            int sl = (ib * 8 + z) * 8 + wave;
            float part = 0.f;
            #pragma unroll
            for (int u = 0; u < 8; ++u)
                part += vreg[u] * ftanh(fmaf((float)p[z][u], PSCALE, qreg[u]));
            #pragma unroll
            for (int o = 32; o; o >>= 1) part += __shfl_xor(part, o);
            if (lane == 0) sc[sl] = part;
        }
    }
    __syncthreads();

    float s0 = (tid < 256) ? sc[tid] : -__builtin_inff();
    float mv = s0;
    #pragma unroll
    for (int o = 32; o; o >>= 1) mv = fmaxf(mv, __shfl_xor(mv, o));
    if (lane == 0) wred[wave] = mv;
    __syncthreads();
    float M = wred[0];
    #pragma unroll
    for (int w = 1; w < 8; ++w) M = fmaxf(M, wred[w]);
    float e0 = (tid < 256) ? __expf(s0 - M) : 0.f;
    if (tid < 256) sc[tid] = e0;
    float sm = e0;
    #pragma unroll
    for (int o = 32; o; o >>= 1) sm += __shfl_xor(sm, o);
    if (lane == 0) wred2[wave] = sm;
    __syncthreads();
    float lsum = wred2[0];
    #pragma unroll
    for (int w = 1; w < 8; ++w) lsum += wred2[w];

    float a8[8] = {};
    for (int ib = 0; ib < 4; ++ib) {
        half8 ev[8];
        float wgt[8];
        #pragma unroll
        for (int z = 0; z < 8; ++z) {
            int sl = (ib * 8 + z) * 8 + wave;
            ev[z] = *(const half8*)(enc_out + ((size_t)b * 512 + sbase + sl) * 512 + lane * 8);
            wgt[z] = sc[sl];
        }
        #pragma unroll
        for (int z = 0; z < 8; ++z)
            #pragma unroll
            for (int u = 0; u < 8; ++u) a8[u] += wgt[z] * (float)ev[z][u];
    }
    #pragma unroll
    for (int u = 0; u < 8; ++u) ctxred[wave][lane * 8 + u] = a8[u];
    __syncthreads();
    float cp = 0.f;
    #pragma unroll
    for (int w = 0; w < 8; ++w) cp += ctxred[w][tid];
    part_ctx[(size_t)ab * 512 + tid] = cp;
    if (tid == 0) { part_m[ab] = M; part_l[ab] = lsum; }

    if (sh == 0 && tid < 128) {
        int tok = trg[b * 128 + tt];
        x_sw[frag_idx(b, tid, 20)] = dec_emb[tok * 128 + tid];
    }
}

// ---------------------------------------------------------------------------
// K_gates: final step (t=126) only -- proven 256-thread kernel.
// ---------------------------------------------------------------------------
__global__ __launch_bounds__(256) void k_gates(
    f16* __restrict__ x_sw, const f16* __restrict__ hprev_sw,
    const f16* __restrict__ wih_sw, const f16* __restrict__ whh_sw,
    const float* __restrict__ dec_b, float* __restrict__ c_ws,
    f16* __restrict__ hnext_sw, f16* __restrict__ hhist_sw,
    const f16* __restrict__ WhT_sw, float* __restrict__ qpart,
    const float* __restrict__ part_m, const float* __restrict__ part_l,
    const float* __restrict__ part_ctx, int t)
{
    int jb = blockIdx.x;
    int j = jb >> 1, mh = jb & 1;
    int tid = threadIdx.x, wave = tid >> 6, lane = tid & 63;
    int col = lane & 15, quad = lane >> 4;
    __shared__ f16 hsl[64][40];
    __shared__ float gm[64][2];

    if (tid < 64) {
        int bb = mh * 64 + tid;
        float m0 = part_m[bb * 2 + 0], m1 = part_m[bb * 2 + 1];
        float l0 = part_l[bb * 2 + 0], l1 = part_l[bb * 2 + 1];
        float M = fmaxf(m0, m1);
        float g0 = __expf(m0 - M), g1 = __expf(m1 - M);
        float inv = 1.f / (g0 * l0 + g1 * l1);
        gm[tid][0] = g0 * inv;
        gm[tid][1] = g1 * inv;
    }
    __syncthreads();
    for (int z = tid; z < 32768; z += 256) {
        int lr = z >> 9, d = z & 511;
        int bb = mh * 64 + lr;
        float c = gm[lr][0] * part_ctx[(size_t)(bb * 2 + 0) * 512 + d]
                + gm[lr][1] * part_ctx[(size_t)(bb * 2 + 1) * 512 + d];
        x_sw[frag_idx(bb, 128 + d, 20)] = (f16)c;
    }
    __syncthreads();

    f32x4 acc[8] = {};
    for (int ks = 0; ks < 36; ++ks) {
        int mtile = mh * 4 + wave;
        half8 a = (ks < 20)
            ? *(const half8*)(x_sw + ((mtile * 20 + ks) * 64 + lane) * 8)
            : *(const half8*)(hprev_sw + ((mtile * 16 + (ks - 20)) * 64 + lane) * 8);
        half8 bv[8];
        #pragma unroll
        for (int jt = 0; jt < 8; ++jt) {
            int g = jt >> 1, u2 = jt & 1;
            int ntile = g * 32 + j * 2 + u2;
            bv[jt] = (ks < 20)
                ? *(const half8*)(wih_sw + ((ntile * 20 + ks) * 64 + lane) * 8)
                : *(const half8*)(whh_sw + ((ntile * 16 + (ks - 20)) * 64 + lane) * 8);
        }
        #pragma unroll
        for (int jt = 0; jt < 8; ++jt)
            acc[jt] = MFMA16(a, bv[jt], acc[jt]);
    }
    float bias[8];
    #pragma unroll
    for (int jt = 0; jt < 8; ++jt) {
        int g = jt >> 1, u2 = jt & 1;
        bias[jt] = dec_b[g * 512 + j * 32 + u2 * 16 + col];
    }
    #pragma unroll
    for (int r = 0; r < 4; ++r) {
        int lb = wave * 16 + quad * 4 + r;
        int bb = mh * 64 + lb;
        #pragma unroll
        for (int u2 = 0; u2 < 2; ++u2) {
            int hl = u2 * 16 + col, hcol = j * 32 + hl;
            float gi = acc[0 + u2][r] + bias[0 + u2];
            float gf = acc[2 + u2][r] + bias[2 + u2];
            float gg = acc[4 + u2][r] + bias[4 + u2];
            float go = acc[6 + u2][r] + bias[6 + u2];
            float ig = fsig(gi), fg = fsig(gf), g2 = ftanh(gg), og = fsig(go);
            float cv = fg * c_ws[bb * 512 + hcol] + ig * g2;
            c_ws[bb * 512 + hcol] = cv;
            float h = og * ftanh(cv);
            f16 h16 = (f16)h;
            int fidx = frag_idx(bb, hcol, 16);
            hnext_sw[fidx] = h16;
            hhist_sw[t * 65536 + fidx] = h16;
            hsl[lb][hl] = h16;
        }
    }
    half8 aq = *(const half8*)(&hsl[wave * 16 + col][quad * 8]);
    for (int nt = 0; nt < 32; ++nt) {
        half8 bq = *(const half8*)(WhT_sw + ((nt * 16 + j) * 64 + lane) * 8);
        f32x4 q0 = {};
        q0 = MFMA16(aq, bq, q0);
        #pragma unroll
        for (int r = 0; r < 4; ++r)
            qpart[(j * 128 + mh * 64 + wave * 16 + quad * 4 + r) * 512 + nt * 16 + col] = q0[r];
    }
}

// ---------------------------------------------------------------------------
// K_logits: batched over all 127 steps (once).
// ---------------------------------------------------------------------------
__global__ __launch_bounds__(256) void k_logits(
    const f16* __restrict__ hhist_sw, const f16* __restrict__ outWT_sw,
    const float* __restrict__ out_b, float* __restrict__ out)
{
    int bt = blockIdx.x;
    int tid = threadIdx.x, wave = tid >> 6, lane = tid & 63;
    int col = lane & 15, quad = lane >> 4;
    f32x4 acc[2][8] = {};
    for (int ks = 0; ks < 16; ++ks) {
        half8 a[2];
        #pragma unroll
        for (int i = 0; i < 2; ++i)
            a[i] = *(const half8*)(hhist_sw + bt * 65536 + (((wave * 2 + i) * 16 + ks) * 64 + lane) * 8);
        half8 bv[8];
        #pragma unroll
        for (int jt = 0; jt < 8; ++jt)
            bv[jt] = *(const half8*)(outWT_sw + ((jt * 16 + ks) * 64 + lane) * 8);
        #pragma unroll
        for (int jt = 0; jt < 8; ++jt) {
            acc[0][jt] = MFMA16(a[0], bv[jt], acc[0][jt]);
            acc[1][jt] = MFMA16(a[1], bv[jt], acc[1][jt]);
        }
    }
    #pragma unroll
    for (int jt = 0; jt < 8; ++jt) {
        float bias = out_b[jt * 16 + col];
        #pragma unroll
        for (int i = 0; i < 2; ++i)
            #pragma unroll
            for (int r = 0; r < 4; ++r) {
                int br = wave * 32 + i * 16 + quad * 4 + r;
                out[br * 16384 + (bt + 1) * 128 + jt * 16 + col] = acc[i][jt][r] + bias;
            }
    }
}

// ---------------------------------------------------------------------------
extern "C" void kernel_launch(void* const* d_in, const int* in_sizes, int n_in,
                              void* d_out, int out_size, void* d_ws, size_t ws_size,
                              hipStream_t stream)
{
    (void)in_sizes; (void)n_in; (void)out_size;
    if (ws_size < 130000000) return;  // clean bail if workspace too small

    const int*   src     = (const int*)d_in[0];
    const int*   trg     = (const int*)d_in[1];
    const float* enc_emb = (const float*)d_in[2];
    const float* wihf    = (const float*)d_in[3];
    const float* whhf    = (const float*)d_in[4];
    const float* bf_     = (const float*)d_in[5];
    const float* wihb    = (const float*)d_in[6];
    const float* whhb    = (const float*)d_in[7];
    const float* bb_     = (const float*)d_in[8];
    const float* dec_emb = (const float*)d_in[9];
    const float* dec_wih = (const float*)d_in[10];
    const float* dec_whh = (const float*)d_in[11];
    const float* dec_b   = (const float*)d_in[12];
    const float* attn_W  = (const float*)d_in[13];
    const float* attn_b  = (const float*)d_in[14];
    const float* attn_v  = (const float*)d_in[15];
    const float* out_W   = (const float*)d_in[16];
    const float* out_b   = (const float*)d_in[17];
    float* out = (float*)d_out;

    char* p = (char*)d_ws;
    auto carve = [&](size_t n) { char* r = p; p += ((n + 255) & ~(size_t)255); return r; };
    f16*   enc_out   = (f16*)  carve(67108864);
    char*  proj8     = (char*) carve(33554432);   // 65536 x 512 int8
    f16*   WhT_sw    = (f16*)  carve(524288);
    f16*   WeT       = (f16*)  carve(524288);
    f16*   outWT_sw  = (f16*)  carve(131072);
    f16*   emb16     = (f16*)  carve(32768);
    f16*   wihf16    = (f16*)  carve(262144);
    f16*   wihb16    = (f16*)  carve(262144);
    f16*   whhf_sw   = (f16*)  carve(524288);
    f16*   whhb_sw   = (f16*)  carve(524288);
    f16*   decemb16  = (f16*)  carve(32768);
    f16*   decwih_sw = (f16*)  carve(2621440);
    f16*   decwhh_sw = (f16*)  carve(2097152);
    float* qpart     = (float*)carve(4194304);
    f16*   hdec0     = (f16*)  carve(131072);
    f16*   hdec1     = (f16*)  carve(131072);
    float* c_ws      = (float*)carve(262144);
    f16*   x_sw      = (f16*)  carve(163840);
    f16*   hhist_sw  = (f16*)  carve(16646144);
    f16*   xg_vocab  = (f16*)  carve(524288);
    float* part_m    = (float*)carve(2048);
    float* part_l    = (float*)carve(2048);
    float* part_ctx  = (float*)carve(524288);
    unsigned* flagsv = (unsigned*)carve(16448);   // 32 producer words, 64B-spaced

    k_zero<<<1, 256, 0, stream>>>(flagsv);
    k_prep<<<14784, 256, 0, stream>>>(attn_W, out_W, enc_emb, wihf, wihb, whhf, whhb,
                                      dec_emb, dec_wih, dec_whh,
                                      WhT_sw, outWT_sw, whhf_sw, whhb_sw,
                                      decwih_sw, decwhh_sw, WeT, emb16,
                                      wihf16, wihb16, decemb16, out);
    k_vocab<<<16, 256, 0, stream>>>(emb16, wihf16, wihb16, bf_, bb_, xg_vocab);
    k_enc<<<16, 512, 0, stream>>>(src, xg_vocab, whhf_sw, whhb_sw, enc_out, hdec0, c_ws);
    k_proj<<<2048, 256, 0, stream>>>(enc_out, WeT, proj8);
    k_qinit<<<16, 256, 0, stream>>>(hdec0, WhT_sw, qpart);

    // decode: one launch per step (gates for t-1 fused ahead of attention t)
    for (int tt = 0; tt < 127; ++tt)
        k_step<<<288, 512, 0, stream>>>(proj8, enc_out, qpart, attn_b, attn_v,
                                        trg, decemb16, x_sw, part_m, part_l,
                                        part_ctx, hdec0, hdec1, decwih_sw,
                                        decwhh_sw, dec_b, c_ws, hhist_sw,
                                        WhT_sw, flagsv, tt);
    // trailing gates for the last step (t=126): hprev = hdec0, hnext = hdec1
    k_gates<<<32, 256, 0, stream>>>(x_sw, hdec0, decwih_sw, decwhh_sw, dec_b,
                                    c_ws, hdec1, hhist_sw, WhT_sw, qpart,
                                    part_m, part_l, part_ctx, 126);

    k_logits<<<127, 256, 0, stream>>>(hhist_sw, outWT_sw, out_b, out);
}

// Round 8
// 10935.269 us; speedup vs baseline: 1.1792x; 1.1445x over previous
//
#include <hip/hip_runtime.h>

// ============================================================================
// Seq2Seq (bi-LSTM encoder + Bahdanau-attention LSTM decoder) on gfx950.
// fp32 in/out; fp16 internal (fp32 accum/state).
// R19 = R18 (12.52 ms) + latency-parallel gates phase:
//   Traffic cuts, dedup, and sync-mechanism changes all moved <3% -- the
//   decode floor is the gates phase's serial latency chain: 36+32+64
//   dependent L2/L3 round-trips at 1 wave/SIMD on 32 CUs (~45 us/step).
//   Fix (numerics identical, same accumulation order):
//     - GEMM on 8 waves (jt-split; g/o gates passed via LDS with bias)
//     - GEMM loads unrolled 4x: 20 independent loads per round, 36->9 rounds
//     - qGEMM nt-split across 8 waves + 4x unrolled bq loads: 32->4 rounds
//     - combine loop unrolled 8x: 64->8 rounds
//   k_enc unchanged (3.5 ms, next target); attention phase unchanged.
// ============================================================================

typedef _Float16 f16;
typedef _Float16 half8 __attribute__((ext_vector_type(8)));
typedef float f32x4 __attribute__((ext_vector_type(4)));
typedef char char8v __attribute__((ext_vector_type(8)));

#define MFMA16(a, b, c) __builtin_amdgcn_mfma_f32_16x16x32_f16((a), (b), (c), 0, 0, 0)

#define PSCALE (2.5f / 127.f)      // int8 proj dequant scale
#define PINV   (127.f / 2.5f)      // quant scale

__device__ __forceinline__ float fsig(float x) {
    return __builtin_amdgcn_rcpf(1.f + __expf(-x));
}
__device__ __forceinline__ float ftanh(float x) {
    return 1.f - 2.f * __builtin_amdgcn_rcpf(1.f + __expf(2.f * x));
}
__device__ __forceinline__ int frag_idx(int m, int k, int KS) {
    return (((m >> 4) * KS + (k >> 5)) * 64 + (((k >> 3) & 3) * 16 + (m & 15))) * 8 + (k & 7);
}

// LDS-only barrier: waits own-wave LDS ops, then barrier.  Deliberately does
// NOT drain vmcnt -- global stores/prefetches stay in flight across steps.
__device__ __forceinline__ void lds_barrier() {
    asm volatile("s_waitcnt lgkmcnt(0)" ::: "memory");
    __builtin_amdgcn_sched_barrier(0);
    __builtin_amdgcn_s_barrier();
    __builtin_amdgcn_sched_barrier(0);
}

// ---------------------------------------------------------------------------
// K_zero: reset flag region (each graph replay).
// flags[i*16] = done-step word for gates block i (i < 32), 64B spacing.
// ---------------------------------------------------------------------------
__global__ void k_zero(unsigned* __restrict__ s)
{
    for (int z = threadIdx.x; z < 4112; z += 256) s[z] = 0u;
}

// ---------------------------------------------------------------------------
// K0: one-shot: pack weights to fragment order (f32 -> f16), plain converts,
// zero out t=0 output row.
// ---------------------------------------------------------------------------
__global__ __launch_bounds__(256) void k_prep(
    const float* __restrict__ attn_W, const float* __restrict__ out_W,
    const float* __restrict__ enc_emb,
    const float* __restrict__ wihf, const float* __restrict__ wihb,
    const float* __restrict__ whhf, const float* __restrict__ whhb,
    const float* __restrict__ dec_emb, const float* __restrict__ dec_wih,
    const float* __restrict__ dec_whh,
    f16* __restrict__ WhT_sw, f16* __restrict__ outWT_sw,
    f16* __restrict__ whhf_sw, f16* __restrict__ whhb_sw,
    f16* __restrict__ decwih_sw, f16* __restrict__ decwhh_sw,
    f16* __restrict__ WeT, f16* __restrict__ emb16,
    f16* __restrict__ wihf16, f16* __restrict__ wihb16,
    f16* __restrict__ decemb16, float* __restrict__ out)
{
    long i = (long)blockIdx.x * 256 + threadIdx.x;
    if (i >= 3784704L) return;
    long idx = i;
    if (idx < 262144) {  // WhT_sw: N=512(e) x K=512(d)
        int j = idx & 7, lane = (idx >> 3) & 63, c = lane & 15, q = lane >> 4;
        int ks = (idx >> 9) & 15, nt = idx >> 13;
        WhT_sw[idx] = (f16)attn_W[(ks * 32 + q * 8 + j) * 512 + nt * 16 + c];
        return;
    }
    idx -= 262144;
    if (idx < 65536) {   // outWT_sw: N=128(v) x K=512(d)
        int j = idx & 7, lane = (idx >> 3) & 63, c = lane & 15, q = lane >> 4;
        int ks = (idx >> 9) & 15, nt = idx >> 13;
        outWT_sw[idx] = (f16)out_W[(ks * 32 + q * 8 + j) * 128 + nt * 16 + c];
        return;
    }
    idx -= 65536;
    if (idx < 262144) {  // whhf_sw: N=1024 x K=256
        int j = idx & 7, lane = (idx >> 3) & 63, c = lane & 15, q = lane >> 4;
        int ks = (idx >> 9) & 7, nt = idx >> 12;
        whhf_sw[idx] = (f16)whhf[(nt * 16 + c) * 256 + ks * 32 + q * 8 + j];
        return;
    }
    idx -= 262144;
    if (idx < 262144) {  // whhb_sw
        int j = idx & 7, lane = (idx >> 3) & 63, c = lane & 15, q = lane >> 4;
        int ks = (idx >> 9) & 7, nt = idx >> 12;
        whhb_sw[idx] = (f16)whhb[(nt * 16 + c) * 256 + ks * 32 + q * 8 + j];
        return;
    }
    idx -= 262144;
    if (idx < 1310720) { // decwih_sw: N=2048 x K=640
        int j = idx & 7, lane = (idx >> 3) & 63, c = lane & 15, q = lane >> 4;
        int r2 = idx >> 9; int ks = r2 % 20, nt = r2 / 20;
        decwih_sw[idx] = (f16)dec_wih[(nt * 16 + c) * 640 + ks * 32 + q * 8 + j];
        return;
    }
    idx -= 1310720;
    if (idx < 1048576) { // decwhh_sw: N=2048 x K=512
        int j = idx & 7, lane = (idx >> 3) & 63, c = lane & 15, q = lane >> 4;
        int ks = (idx >> 9) & 15, nt = idx >> 13;
        decwhh_sw[idx] = (f16)dec_whh[(nt * 16 + c) * 512 + ks * 32 + q * 8 + j];
        return;
    }
    idx -= 1048576;
    if (idx < 262144) { int e = idx >> 9, d = idx & 511; WeT[idx] = (f16)attn_W[(512 + d) * 512 + e]; return; }
    idx -= 262144;
    if (idx < 16384)  { emb16[idx] = (f16)enc_emb[idx]; return; }
    idx -= 16384;
    if (idx < 131072) { wihf16[idx] = (f16)wihf[idx]; return; }
    idx -= 131072;
    if (idx < 131072) { wihb16[idx] = (f16)wihb[idx]; return; }
    idx -= 131072;
    if (idx < 16384)  { decemb16[idx] = (f16)dec_emb[idx]; return; }
    idx -= 16384;
    if (idx < 16384)  { int b = idx >> 7, v = idx & 127; out[b * 16384 + v] = 0.f; return; }
}

// ---------------------------------------------------------------------------
// K_vocab: xg_vocab[v][n] = emb[v] @ [Wih_f|Wih_b]^T + [b_f|b_b] (once).
// ---------------------------------------------------------------------------
__global__ __launch_bounds__(256) void k_vocab(
    const f16* __restrict__ emb, const f16* __restrict__ wihf,
    const f16* __restrict__ wihb, const float* __restrict__ bf_,
    const float* __restrict__ bb_, f16* __restrict__ xg_vocab)
{
    int bn = blockIdx.x;
    int tid = threadIdx.x, wave = tid >> 6, lane = tid & 63;
    int col = lane & 15, quad = lane >> 4;
    int wr = wave >> 1, wc = wave & 1;

    f32x4 acc[4][4] = {};
    for (int ks = 0; ks < 4; ++ks) {
        int k0 = ks * 32 + quad * 8;
        half8 a[4], bfr[4];
        for (int i = 0; i < 4; ++i)
            a[i] = *(const half8*)(emb + (wr * 64 + i * 16 + col) * 128 + k0);
        for (int j = 0; j < 4; ++j) {
            int n = bn * 128 + wc * 64 + j * 16 + col;
            const f16* wp = (n < 1024) ? (wihf + n * 128) : (wihb + (n - 1024) * 128);
            bfr[j] = *(const half8*)(wp + k0);
        }
        for (int i = 0; i < 4; ++i)
            for (int j = 0; j < 4; ++j)
                acc[i][j] = MFMA16(a[i], bfr[j], acc[i][j]);
    }
    for (int j = 0; j < 4; ++j) {
        int n = bn * 128 + wc * 64 + j * 16 + col;
        float bias = (n < 1024) ? bf_[n] : bb_[n - 1024];
        for (int i = 0; i < 4; ++i) {
            int vbase = wr * 64 + i * 16 + quad * 4;
            for (int r = 0; r < 4; ++r)
                xg_vocab[(vbase + r) * 2048 + n] = (f16)(acc[i][j][r] + bias);
        }
    }
}

// ---------------------------------------------------------------------------
// K_enc (R16 form): encoder scan, 16 blocks, 512 threads, one lgkm-only
// barrier per t-step; hb/xvb double-buffered; no vmcnt drain in-loop.
// ---------------------------------------------------------------------------
__global__ __launch_bounds__(512, 1) void k_enc(
    const int* __restrict__ src, const f16* __restrict__ xg_vocab,
    const f16* __restrict__ whhf_sw, const f16* __restrict__ whhb_sw,
    f16* __restrict__ enc_out, f16* __restrict__ hdec0, float* __restrict__ c_ws)
{
    int blk = blockIdx.x;
    int dir = blk >> 3, bbase = (blk & 7) * 16;
    int tid = threadIdx.x, wave = tid >> 6, lane = tid & 63;
    int col = lane & 15, quad = lane >> 4;
    const f16* whh = dir ? whhb_sw : whhf_sw;

    __shared__ f16 hb[2][16][264];
    __shared__ f16 xvb[2][16][1032];
    __shared__ unsigned short stall[8192];   // [b][t] tokens (VIN=128 fits u16)

    for (int z = tid; z < 2 * 16 * 264; z += 512) ((f16*)hb)[z] = (f16)0.f;
    for (int z = tid; z < 8192; z += 512) stall[z] = (unsigned short)src[bbase * 512 + z];
    float cc[2][4] = {};

    // gate-0 Whh fragments resident in VGPRs: 16 half8 = 64 VGPR
    half8 bst[16];
    #pragma unroll
    for (int nt = 0; nt < 2; ++nt)
        #pragma unroll
        for (int kk = 0; kk < 8; ++kk) {
            int tile = wave * 2 + nt;
            bst[nt * 8 + kk] = *(const half8*)(whh + ((tile * 8 + kk) * 64 + lane) * 8);
        }
    __syncthreads();

    int xrow = tid >> 7, xoff = (tid & 127) * 8;
    half8 xr[4];
    {
        int ts0 = dir ? 511 : 0;
        #pragma unroll
        for (int it = 0; it < 4; ++it) {
            int row = it * 4 + xrow;
            int tok = stall[row * 512 + ts0];
            xr[it] = *(const half8*)(xg_vocab + tok * 2048 + dir * 1024 + xoff);
        }
        #pragma unroll
        for (int it = 0; it < 4; ++it)
            *(half8*)(&xvb[0][it * 4 + xrow][xoff]) = xr[it];
    }
    __syncthreads();

    int ts_prev = 0;
    for (int t = 0; t < 512; ++t) {
        int ts = dir ? (511 - t) : t;
        int cur = t & 1, prv = cur ^ 1;

        if (t < 511) {
            int tsn = dir ? (510 - t) : (t + 1);
            #pragma unroll
            for (int it = 0; it < 4; ++it) {
                int row = it * 4 + xrow;
                int tok = stall[row * 512 + tsn];
                xr[it] = *(const half8*)(xg_vocab + tok * 2048 + dir * 1024 + xoff);
            }
        }

        if (t > 0) {
            int b = tid >> 5, seg = tid & 31;
            *(half8*)(enc_out + ((size_t)(bbase + b) * 512 + ts_prev) * 512 + dir * 256 + seg * 8) =
                *(const half8*)(&hb[prv][b][seg * 8]);
        }

        half8 a[8];
        #pragma unroll
        for (int kk = 0; kk < 8; ++kk)
            a[kk] = *(const half8*)(&hb[prv][col][kk * 32 + quad * 8]);

        f32x4 acc[4][2] = {};
        #pragma unroll
        for (int kk = 0; kk < 8; ++kk) {
            half8 bv[6];
            #pragma unroll
            for (int g = 1; g < 4; ++g)
                #pragma unroll
                for (int nt = 0; nt < 2; ++nt) {
                    int tile = g * 16 + wave * 2 + nt;
                    bv[(g - 1) * 2 + nt] =
                        *(const half8*)(whh + ((tile * 8 + kk) * 64 + lane) * 8);
                }
            #pragma unroll
            for (int nt = 0; nt < 2; ++nt)
                acc[0][nt] = MFMA16(a[kk], bst[nt * 8 + kk], acc[0][nt]);
            #pragma unroll
            for (int g = 1; g < 4; ++g)
                #pragma unroll
                for (int nt = 0; nt < 2; ++nt)
                    acc[g][nt] = MFMA16(a[kk], bv[(g - 1) * 2 + nt], acc[g][nt]);
        }

        #pragma unroll
        for (int nt = 0; nt < 2; ++nt) {
            int hcol = wave * 32 + nt * 16 + col;
            #pragma unroll
            for (int r = 0; r < 4; ++r) {
                int b = quad * 4 + r;
                float gi = (float)xvb[cur][b][0 * 256 + hcol] + acc[0][nt][r];
                float gf = (float)xvb[cur][b][1 * 256 + hcol] + acc[1][nt][r];
                float gg = (float)xvb[cur][b][2 * 256 + hcol] + acc[2][nt][r];
                float go = (float)xvb[cur][b][3 * 256 + hcol] + acc[3][nt][r];
                float ig = fsig(gi), fg = fsig(gf), g2 = ftanh(gg), og = fsig(go);
                float cv = fg * cc[nt][r] + ig * g2;
                cc[nt][r] = cv;
                float h = og * ftanh(cv);
                hb[cur][b][hcol] = (f16)h;
            }
        }

        if (t < 511) {
            #pragma unroll
            for (int it = 0; it < 4; ++it)
                *(half8*)(&xvb[prv][it * 4 + xrow][xoff]) = xr[it];
        }

        lds_barrier();
        ts_prev = ts;
    }

    {
        int b = tid >> 5, seg = tid & 31;
        *(half8*)(enc_out + ((size_t)(bbase + b) * 512 + ts_prev) * 512 + dir * 256 + seg * 8) =
            *(const half8*)(&hb[1][b][seg * 8]);
    }
    #pragma unroll
    for (int nt = 0; nt < 2; ++nt) {
        int hcol = wave * 32 + nt * 16 + col;
        #pragma unroll
        for (int r = 0; r < 4; ++r) {
            int b = quad * 4 + r;
            int m = bbase + b, k = dir * 256 + hcol;
            hdec0[frag_idx(m, k, 16)] = hb[1][b][hcol];
            c_ws[m * 512 + k] = cc[nt][r];
        }
    }
}

// ---------------------------------------------------------------------------
// K_proj: enc_proj = enc_out @ We (once).  Writes int8 (fixed scale).
// ---------------------------------------------------------------------------
__global__ __launch_bounds__(256) void k_proj(
    const f16* __restrict__ enc_out, const f16* __restrict__ WeT,
    char* __restrict__ proj8)
{
    int blk = blockIdx.x;
    int bm = blk & 511, bn = blk >> 9;
    int tid = threadIdx.x, wave = tid >> 6, lane = tid & 63;
    int col = lane & 15, quad = lane >> 4;
    int wr = wave >> 1, wc = wave & 1;

    f32x4 acc[4][4] = {};
    for (int ks = 0; ks < 16; ++ks) {
        int k0 = ks * 32 + quad * 8;
        half8 a[4], bfr[4];
        for (int i = 0; i < 4; ++i) {
            int m = bm * 128 + wr * 64 + i * 16 + col;
            a[i] = *(const half8*)(enc_out + (size_t)m * 512 + k0);
        }
        for (int j = 0; j < 4; ++j) {
            int n = bn * 128 + wc * 64 + j * 16 + col;
            bfr[j] = *(const half8*)(WeT + n * 512 + k0);
        }
        for (int i = 0; i < 4; ++i)
            for (int j = 0; j < 4; ++j)
                acc[i][j] = MFMA16(a[i], bfr[j], acc[i][j]);
    }
    for (int j = 0; j < 4; ++j) {
        int n = bn * 128 + wc * 64 + j * 16 + col;
        for (int i = 0; i < 4; ++i) {
            int mbase = bm * 128 + wr * 64 + i * 16 + quad * 4;
            for (int r = 0; r < 4; ++r) {
                float v = acc[i][j][r] * PINV;
                int q = (int)rintf(v);
                q = (q > 127) ? 127 : ((q < -127) ? -127 : q);
                proj8[(size_t)(mbase + r) * 512 + n] = (char)q;
            }
        }
    }
}

// ---------------------------------------------------------------------------
// K_qinit: initial q-partials (once).
// ---------------------------------------------------------------------------
__global__ __launch_bounds__(256) void k_qinit(
    const f16* __restrict__ h0_sw, const f16* __restrict__ WhT_sw,
    float* __restrict__ qpart)
{
    int j = blockIdx.x;
    int tid = threadIdx.x, wave = tid >> 6, lane = tid & 63;
    int col = lane & 15, quad = lane >> 4;
    half8 a[2];
    #pragma unroll
    for (int i = 0; i < 2; ++i)
        a[i] = *(const half8*)(h0_sw + (((wave * 2 + i) * 16 + j) * 64 + lane) * 8);
    for (int nt = 0; nt < 32; ++nt) {
        half8 bfr = *(const half8*)(WhT_sw + ((nt * 16 + j) * 64 + lane) * 8);
        f32x4 q0 = {}, q1 = {};
        q0 = MFMA16(a[0], bfr, q0);
        q1 = MFMA16(a[1], bfr, q1);
        #pragma unroll
        for (int r = 0; r < 4; ++r) {
            qpart[(j * 128 + wave * 32 + quad * 4 + r) * 512 + nt * 16 + col] = q0[r];
            qpart[(j * 128 + wave * 32 + 16 + quad * 4 + r) * 512 + nt * 16 + col] = q1[r];
        }
    }
}

// ---------------------------------------------------------------------------
// K_step (launch tt = 0..126): blocks 0..31 run the LSTM-gates phase for
// step tt-1 (skipped at tt=0), each releasing its OWN flag word; blocks
// 32..287 run the attention phase for step tt after a parallel sweep-poll.
// R19 gates phase: 8 waves (jt-split via LDS), 4x-unrolled batched loads in
// GEMM/qGEMM/combine -- dependent memory rounds 132 -> ~21.
// ---------------------------------------------------------------------------
__global__ __launch_bounds__(512, 2) void k_step(
    const char* __restrict__ proj8, const f16* __restrict__ enc_out,
    float* __restrict__ qpart, const float* __restrict__ attn_bp,
    const float* __restrict__ attn_vp, const int* __restrict__ trg,
    const f16* __restrict__ dec_emb, f16* __restrict__ x_sw,
    float* __restrict__ part_m, float* __restrict__ part_l,
    float* __restrict__ part_ctx, f16* __restrict__ hdec0,
    f16* __restrict__ hdec1, const f16* __restrict__ wih_sw,
    const f16* __restrict__ whh_sw, const float* __restrict__ dec_bp,
    float* __restrict__ c_ws, f16* __restrict__ hhist_sw,
    const f16* __restrict__ WhT_sw, unsigned* __restrict__ flags, int tt)
{
    int blk = blockIdx.x;
    int tid = threadIdx.x, wave = tid >> 6, lane = tid & 63;
    int col = lane & 15, quad = lane >> 4;

    __shared__ float q[512];
    __shared__ float sc[256];
    __shared__ float ctxred[8][512];
    __shared__ float wred[8], wred2[8];
    __shared__ f16 hsl[64][40];
    __shared__ float gm[64][2];
    __shared__ float gq[4][4][4][64];   // g/o gates (bias added) from waves 4-7

    if (blk < 32) {
        // ============ gates phase: step tg = tt-1 (blocks 0..31) ============
        int tg = tt - 1;
        if (tg >= 0) {
            int j = blk >> 1, mh = blk & 1;
            if (tid < 64) {
                int bb = mh * 64 + tid;
                float m0 = part_m[bb * 2 + 0], m1 = part_m[bb * 2 + 1];
                float l0 = part_l[bb * 2 + 0], l1 = part_l[bb * 2 + 1];
                float M = fmaxf(m0, m1);
                float g0 = __expf(m0 - M), g1 = __expf(m1 - M);
                float inv = 1.f / (g0 * l0 + g1 * l1);
                gm[tid][0] = g0 * inv;
                gm[tid][1] = g1 * inv;
            }
            __syncthreads();

            // combine: i = row 0..63, d = tid; 8 rounds of 16 batched loads
            for (int io = 0; io < 64; io += 8) {
                float p0[8], p1[8];
                #pragma unroll
                for (int k = 0; k < 8; ++k) {
                    int bb = mh * 64 + io + k;
                    p0[k] = part_ctx[(size_t)(bb * 2 + 0) * 512 + tid];
                    p1[k] = part_ctx[(size_t)(bb * 2 + 1) * 512 + tid];
                }
                #pragma unroll
                for (int k = 0; k < 8; ++k) {
                    int lr = io + k, bb = mh * 64 + lr;
                    x_sw[frag_idx(bb, 128 + tid, 20)] =
                        (f16)(gm[lr][0] * p0[k] + gm[lr][1] * p1[k]);
                }
            }
            __syncthreads();

            const f16* hprev = (tg & 1) ? hdec1 : hdec0;
            f16* hnext = (tg & 1) ? hdec0 : hdec1;

            int h = wave >> 2, mw = wave & 3;   // jt-half, m-tile-in-half
            int mtile = mh * 4 + mw;

            // GEMM: wave computes acc[q2] = gates jt = h*4 + q2 for its m-tile.
            f32x4 acc[4] = {};
            // ks 0..19 (x_sw A, wih B): 5 groups of 4
            for (int kg = 0; kg < 20; kg += 4) {
                half8 ag[4], bvg[4][4];
                #pragma unroll
                for (int kk = 0; kk < 4; ++kk) {
                    int ks = kg + kk;
                    ag[kk] = *(const half8*)(x_sw + ((mtile * 20 + ks) * 64 + lane) * 8);
                    #pragma unroll
                    for (int q2 = 0; q2 < 4; ++q2) {
                        int jt = h * 4 + q2, g = jt >> 1, u2 = jt & 1;
                        int ntile = g * 32 + j * 2 + u2;
                        bvg[kk][q2] = *(const half8*)(wih_sw + ((ntile * 20 + ks) * 64 + lane) * 8);
                    }
                }
                #pragma unroll
                for (int kk = 0; kk < 4; ++kk)
                    #pragma unroll
                    for (int q2 = 0; q2 < 4; ++q2)
                        acc[q2] = MFMA16(ag[kk], bvg[kk][q2], acc[q2]);
            }
            // ks 20..35 (hprev A, whh B): 4 groups of 4
            for (int kg = 0; kg < 16; kg += 4) {
                half8 ag[4], bvg[4][4];
                #pragma unroll
                for (int kk = 0; kk < 4; ++kk) {
                    int ks2 = kg + kk;
                    ag[kk] = *(const half8*)(hprev + ((mtile * 16 + ks2) * 64 + lane) * 8);
                    #pragma unroll
                    for (int q2 = 0; q2 < 4; ++q2) {
                        int jt = h * 4 + q2, g = jt >> 1, u2 = jt & 1;
                        int ntile = g * 32 + j * 2 + u2;
                        bvg[kk][q2] = *(const half8*)(whh_sw + ((ntile * 16 + ks2) * 64 + lane) * 8);
                    }
                }
                #pragma unroll
                for (int kk = 0; kk < 4; ++kk)
                    #pragma unroll
                    for (int q2 = 0; q2 < 4; ++q2)
                        acc[q2] = MFMA16(ag[kk], bvg[kk][q2], acc[q2]);
            }

            float bias[4];
            #pragma unroll
            for (int q2 = 0; q2 < 4; ++q2) {
                int jt = h * 4 + q2, g = jt >> 1, u2 = jt & 1;
                bias[q2] = dec_bp[g * 512 + j * 32 + u2 * 16 + col];
            }
            if (h == 1) {
                #pragma unroll
                for (int q2 = 0; q2 < 4; ++q2)
                    #pragma unroll
                    for (int r = 0; r < 4; ++r)
                        gq[mw][q2][r][lane] = acc[q2][r] + bias[q2];
            }
            __syncthreads();

            if (h == 0) {
                // LSTM epilogue: gi/gf from own acc, gg/go from gq
                #pragma unroll
                for (int r = 0; r < 4; ++r) {
                    int lb = mw * 16 + quad * 4 + r;
                    int bb = mh * 64 + lb;
                    #pragma unroll
                    for (int u2 = 0; u2 < 2; ++u2) {
                        int hl = u2 * 16 + col, hcol = j * 32 + hl;
                        float gi = acc[0 + u2][r] + bias[0 + u2];
                        float gf = acc[2 + u2][r] + bias[2 + u2];
                        float gg = gq[mw][0 + u2][r][lane];
                        float go = gq[mw][2 + u2][r][lane];
                        float ig = fsig(gi), fg = fsig(gf), g2 = ftanh(gg), og = fsig(go);
                        float cv = fg * c_ws[bb * 512 + hcol] + ig * g2;
                        c_ws[bb * 512 + hcol] = cv;
                        float hv = og * ftanh(cv);
                        f16 h16 = (f16)hv;
                        int fidx = frag_idx(bb, hcol, 16);
                        hnext[fidx] = h16;
                        hhist_sw[tg * 65536 + fidx] = h16;
                        hsl[lb][hl] = h16;
                    }
                }
            }
            __syncthreads();

            // qGEMM: 8 waves; wave (h,mw): nt in [h*16, h*16+16), 4 groups of 4
            half8 aq = *(const half8*)(&hsl[mw * 16 + col][quad * 8]);
            for (int ng = 0; ng < 4; ++ng) {
                half8 bq[4];
                #pragma unroll
                for (int k = 0; k < 4; ++k) {
                    int nt = h * 16 + ng * 4 + k;
                    bq[k] = *(const half8*)(WhT_sw + ((nt * 16 + j) * 64 + lane) * 8);
                }
                #pragma unroll
                for (int k = 0; k < 4; ++k) {
                    int nt = h * 16 + ng * 4 + k;
                    f32x4 q0 = {};
                    q0 = MFMA16(aq, bq[k], q0);
                    #pragma unroll
                    for (int r = 0; r < 4; ++r)
                        qpart[(j * 128 + mh * 64 + mw * 16 + quad * 4 + r) * 512 + nt * 16 + col] = q0[r];
                }
            }

            // ---- release: this block's own flag word (no shared counter) ----
            __syncthreads();
            if (tid == 0)
                __hip_atomic_store(flags + blk * 16, (unsigned)tt,
                                   __ATOMIC_RELEASE, __HIP_MEMORY_SCOPE_AGENT);
        }
        return;
    }

    // ================= attention phase: step tt (blocks 32..287) =================
    int ab = blk - 32;
    int b = ab >> 1, sh = ab & 1;
    int sbase = sh * 256;

    float vreg[8];
    #pragma unroll
    for (int u = 0; u < 8; ++u) vreg[u] = attn_vp[lane * 8 + u];
    float abias = attn_bp[tid];

    // prefetch ib=0 proj8 rows (flag-independent) while producers finish
    char8v p0[8];
    #pragma unroll
    for (int z = 0; z < 8; ++z) {
        int sl = z * 8 + wave;
        p0[z] = *(const char8v*)(proj8 + ((size_t)b * 512 + sbase + sl) * 512 + lane * 8);
    }

    if (tt > 0) {
        // sweep-poll all 32 producer words in one wave-instr (lanes 0..31)
        if (wave == 0) {
            for (;;) {
                unsigned v = (lane < 32)
                    ? __hip_atomic_load(flags + lane * 16, __ATOMIC_RELAXED,
                                        __HIP_MEMORY_SCOPE_AGENT)
                    : (unsigned)tt;
                if (__ballot(v >= (unsigned)tt) == ~0ull) break;
                __builtin_amdgcn_s_sleep(8);
            }
            if (lane == 0)
                (void)__hip_atomic_load(flags, __ATOMIC_ACQUIRE,
                                        __HIP_MEMORY_SCOPE_AGENT);
        }
        __syncthreads();
    }

    {
        float s = abias;
        #pragma unroll
        for (int jj = 0; jj < 16; ++jj) s += qpart[(jj * 128 + b) * 512 + tid];
        q[tid] = s;
    }
    __syncthreads();

    float qreg[8];
    #pragma unroll
    for (int u = 0; u < 8; ++u) qreg[u] = q[lane * 8 + u];

    // scores ib=0 from the prefetched registers
    #pragma unroll
    for (int z = 0; z < 8; ++z) {
        int sl = z * 8 + wave;
        float part = 0.f;
        #pragma unroll
        for (int u = 0; u < 8; ++u)
            part += vreg[u] * ftanh(fmaf((float)p0[z][u], PSCALE, qreg[u]));
        #pragma unroll
        for (int o = 32; o; o >>= 1) part += __shfl_xor(part, o);
        if (lane == 0) sc[sl] = part;
    }
    // scores ib=1..3
    for (int ib = 1; ib < 4; ++ib) {
        char8v p[8];
        #pragma unroll
        for (int z = 0; z < 8; ++z) {
            int sl = (ib * 8 + z) * 8 + wave;
            p[z] = *(const char8v*)(proj8 + ((size_t)b * 512 + sbase + sl) * 512 + lane * 8);
        }
        #pragma unroll
        for (int z = 0; z < 8; ++z) {
            int sl = (ib * 8 + z) * 8 + wave;
            float part = 0.f;
            #pragma unroll
            for (int u = 0; u < 8; ++u)
                part += vreg[u] * ftanh(fmaf((float)p[z][u], PSCALE, qreg[u]));
            #pragma unroll
            for (int o = 32; o; o >>= 1) part += __shfl_xor(part, o);
            if (lane == 0) sc[sl] = part;
        }
    }
    __syncthreads();

    float s0 = (tid < 256) ? sc[tid] : -__builtin_inff();
    float mv = s0;
    #pragma unroll
    for (int o = 32; o; o >>= 1) mv = fmaxf(mv, __shfl_xor(mv, o));
    if (lane == 0) wred[wave] = mv;
    __syncthreads();
    float M = wred[0];
    #pragma unroll
    for (int w = 1; w < 8; ++w) M = fmaxf(M, wred[w]);
    float e0 = (tid < 256) ? __expf(s0 - M) : 0.f;
    if (tid < 256) sc[tid] = e0;
    float sm = e0;
    #pragma unroll
    for (int o = 32; o; o >>= 1) sm += __shfl_xor(sm, o);
    if (lane == 0) wred2[wave] = sm;
    __syncthreads();
    float lsum = wred2[0];
    #pragma unroll
    for (int w = 1; w < 8; ++w) lsum += wred2[w];

    float a8[8] = {};
    for (int ib = 0; ib < 4; ++ib) {
        half8 ev[8];
        float wgt[8];
        #pragma unroll
        for (int z = 0; z < 8; ++z) {
            int sl = (ib * 8 + z) * 8 + wave;
            ev[z] = *(const half8*)(enc_out + ((size_t)b * 512 + sbase + sl) * 512 + lane * 8);
            wgt[z] = sc[sl];
        }
        #pragma unroll
        for (int z = 0; z < 8; ++z)
            #pragma unroll
            for (int u = 0; u < 8; ++u) a8[u] += wgt[z] * (float)ev[z][u];
    }
    #pragma unroll
    for (int u = 0; u < 8; ++u) ctxred[wave][lane * 8 + u] = a8[u];
    __syncthreads();
    float cp = 0.f;
    #pragma unroll
    for (int w = 0; w < 8; ++w) cp += ctxred[w][tid];
    part_ctx[(size_t)ab * 512 + tid] = cp;
    if (tid == 0) { part_m[ab] = M; part_l[ab] = lsum; }

    if (sh == 0 && tid < 128) {
        int tok = trg[b * 128 + tt];
        x_sw[frag_idx(b, tid, 20)] = dec_emb[tok * 128 + tid];
    }
}

// ---------------------------------------------------------------------------
// K_gates: final step (t=126) only -- proven 256-thread kernel.
// ---------------------------------------------------------------------------
__global__ __launch_bounds__(256) void k_gates(
    f16* __restrict__ x_sw, const f16* __restrict__ hprev_sw,
    const f16* __restrict__ wih_sw, const f16* __restrict__ whh_sw,
    const float* __restrict__ dec_b, float* __restrict__ c_ws,
    f16* __restrict__ hnext_sw, f16* __restrict__ hhist_sw,
    const f16* __restrict__ WhT_sw, float* __restrict__ qpart,
    const float* __restrict__ part_m, const float* __restrict__ part_l,
    const float* __restrict__ part_ctx, int t)
{
    int jb = blockIdx.x;
    int j = jb >> 1, mh = jb & 1;
    int tid = threadIdx.x, wave = tid >> 6, lane = tid & 63;
    int col = lane & 15, quad = lane >> 4;
    __shared__ f16 hsl[64][40];
    __shared__ float gm[64][2];

    if (tid < 64) {
        int bb = mh * 64 + tid;
        float m0 = part_m[bb * 2 + 0], m1 = part_m[bb * 2 + 1];
        float l0 = part_l[bb * 2 + 0], l1 = part_l[bb * 2 + 1];
        float M = fmaxf(m0, m1);
        float g0 = __expf(m0 - M), g1 = __expf(m1 - M);
        float inv = 1.f / (g0 * l0 + g1 * l1);
        gm[tid][0] = g0 * inv;
        gm[tid][1] = g1 * inv;
    }
    __syncthreads();
    for (int z = tid; z < 32768; z += 256) {
        int lr = z >> 9, d = z & 511;
        int bb = mh * 64 + lr;
        float c = gm[lr][0] * part_ctx[(size_t)(bb * 2 + 0) * 512 + d]
                + gm[lr][1] * part_ctx[(size_t)(bb * 2 + 1) * 512 + d];
        x_sw[frag_idx(bb, 128 + d, 20)] = (f16)c;
    }
    __syncthreads();

    f32x4 acc[8] = {};
    for (int ks = 0; ks < 36; ++ks) {
        int mtile = mh * 4 + wave;
        half8 a = (ks < 20)
            ? *(const half8*)(x_sw + ((mtile * 20 + ks) * 64 + lane) * 8)
            : *(const half8*)(hprev_sw + ((mtile * 16 + (ks - 20)) * 64 + lane) * 8);
        half8 bv[8];
        #pragma unroll
        for (int jt = 0; jt < 8; ++jt) {
            int g = jt >> 1, u2 = jt & 1;
            int ntile = g * 32 + j * 2 + u2;
            bv[jt] = (ks < 20)
                ? *(const half8*)(wih_sw + ((ntile * 20 + ks) * 64 + lane) * 8)
                : *(const half8*)(whh_sw + ((ntile * 16 + (ks - 20)) * 64 + lane) * 8);
        }
        #pragma unroll
        for (int jt = 0; jt < 8; ++jt)
            acc[jt] = MFMA16(a, bv[jt], acc[jt]);
    }
    float bias[8];
    #pragma unroll
    for (int jt = 0; jt < 8; ++jt) {
        int g = jt >> 1, u2 = jt & 1;
        bias[jt] = dec_b[g * 512 + j * 32 + u2 * 16 + col];
    }
    #pragma unroll
    for (int r = 0; r < 4; ++r) {
        int lb = wave * 16 + quad * 4 + r;
        int bb = mh * 64 + lb;
        #pragma unroll
        for (int u2 = 0; u2 < 2; ++u2) {
            int hl = u2 * 16 + col, hcol = j * 32 + hl;
            float gi = acc[0 + u2][r] + bias[0 + u2];
            float gf = acc[2 + u2][r] + bias[2 + u2];
            float gg = acc[4 + u2][r] + bias[4 + u2];
            float go = acc[6 + u2][r] + bias[6 + u2];
            float ig = fsig(gi), fg = fsig(gf), g2 = ftanh(gg), og = fsig(go);
            float cv = fg * c_ws[bb * 512 + hcol] + ig * g2;
            c_ws[bb * 512 + hcol] = cv;
            float h = og * ftanh(cv);
            f16 h16 = (f16)h;
            int fidx = frag_idx(bb, hcol, 16);
            hnext_sw[fidx] = h16;
            hhist_sw[t * 65536 + fidx] = h16;
            hsl[lb][hl] = h16;
        }
    }
    half8 aq = *(const half8*)(&hsl[wave * 16 + col][quad * 8]);
    for (int nt = 0; nt < 32; ++nt) {
        half8 bq = *(const half8*)(WhT_sw + ((nt * 16 + j) * 64 + lane) * 8);
        f32x4 q0 = {};
        q0 = MFMA16(aq, bq, q0);
        #pragma unroll
        for (int r = 0; r < 4; ++r)
            qpart[(j * 128 + mh * 64 + wave * 16 + quad * 4 + r) * 512 + nt * 16 + col] = q0[r];
    }
}

// ---------------------------------------------------------------------------
// K_logits: batched over all 127 steps (once).
// ---------------------------------------------------------------------------
__global__ __launch_bounds__(256) void k_logits(
    const f16* __restrict__ hhist_sw, const f16* __restrict__ outWT_sw,
    const float* __restrict__ out_b, float* __restrict__ out)
{
    int bt = blockIdx.x;
    int tid = threadIdx.x, wave = tid >> 6, lane = tid & 63;
    int col = lane & 15, quad = lane >> 4;
    f32x4 acc[2][8] = {};
    for (int ks = 0; ks < 16; ++ks) {
        half8 a[2];
        #pragma unroll
        for (int i = 0; i < 2; ++i)
            a[i] = *(const half8*)(hhist_sw + bt * 65536 + (((wave * 2 + i) * 16 + ks) * 64 + lane) * 8);
        half8 bv[8];
        #pragma unroll
        for (int jt = 0; jt < 8; ++jt)
            bv[jt] = *(const half8*)(outWT_sw + ((jt * 16 + ks) * 64 + lane) * 8);
        #pragma unroll
        for (int jt = 0; jt < 8; ++jt) {
            acc[0][jt] = MFMA16(a[0], bv[jt], acc[0][jt]);
            acc[1][jt] = MFMA16(a[1], bv[jt], acc[1][jt]);
        }
    }
    #pragma unroll
    for (int jt = 0; jt < 8; ++jt) {
        float bias = out_b[jt * 16 + col];
        #pragma unroll
        for (int i = 0; i < 2; ++i)
            #pragma unroll
            for (int r = 0; r < 4; ++r) {
                int br = wave * 32 + i * 16 + quad * 4 + r;
                out[br * 16384 + (bt + 1) * 128 + jt * 16 + col] = acc[i][jt][r] + bias;
            }
    }
}

// ---------------------------------------------------------------------------
extern "C" void kernel_launch(void* const* d_in, const int* in_sizes, int n_in,
                              void* d_out, int out_size, void* d_ws, size_t ws_size,
                              hipStream_t stream)
{
    (void)in_sizes; (void)n_in; (void)out_size;
    if (ws_size < 130000000) return;  // clean bail if workspace too small

    const int*   src     = (const int*)d_in[0];
    const int*   trg     = (const int*)d_in[1];
    const float* enc_emb = (const float*)d_in[2];
    const float* wihf    = (const float*)d_in[3];
    const float* whhf    = (const float*)d_in[4];
    const float* bf_     = (const float*)d_in[5];
    const float* wihb    = (const float*)d_in[6];
    const float* whhb    = (const float*)d_in[7];
    const float* bb_     = (const float*)d_in[8];
    const float* dec_emb = (const float*)d_in[9];
    const float* dec_wih = (const float*)d_in[10];
    const float* dec_whh = (const float*)d_in[11];
    const float* dec_b   = (const float*)d_in[12];
    const float* attn_W  = (const float*)d_in[13];
    const float* attn_b  = (const float*)d_in[14];
    const float* attn_v  = (const float*)d_in[15];
    const float* out_W   = (const float*)d_in[16];
    const float* out_b   = (const float*)d_in[17];
    float* out = (float*)d_out;

    char* p = (char*)d_ws;
    auto carve = [&](size_t n) { char* r = p; p += ((n + 255) & ~(size_t)255); return r; };
    f16*   enc_out   = (f16*)  carve(67108864);
    char*  proj8     = (char*) carve(33554432);   // 65536 x 512 int8
    f16*   WhT_sw    = (f16*)  carve(524288);
    f16*   WeT       = (f16*)  carve(524288);
    f16*   outWT_sw  = (f16*)  carve(131072);
    f16*   emb16     = (f16*)  carve(32768);
    f16*   wihf16    = (f16*)  carve(262144);
    f16*   wihb16    = (f16*)  carve(262144);
    f16*   whhf_sw   = (f16*)  carve(524288);
    f16*   whhb_sw   = (f16*)  carve(524288);
    f16*   decemb16  = (f16*)  carve(32768);
    f16*   decwih_sw = (f16*)  carve(2621440);
    f16*   decwhh_sw = (f16*)  carve(2097152);
    float* qpart     = (float*)carve(4194304);
    f16*   hdec0     = (f16*)  carve(131072);
    f16*   hdec1     = (f16*)  carve(131072);
    float* c_ws      = (float*)carve(262144);
    f16*   x_sw      = (f16*)  carve(163840);
    f16*   hhist_sw  = (f16*)  carve(16646144);
    f16*   xg_vocab  = (f16*)  carve(524288);
    float* part_m    = (float*)carve(2048);
    float* part_l    = (float*)carve(2048);
    float* part_ctx  = (float*)carve(524288);
    unsigned* flagsv = (unsigned*)carve(16448);   // 32 producer words, 64B-spaced

    k_zero<<<1, 256, 0, stream>>>(flagsv);
    k_prep<<<14784, 256, 0, stream>>>(attn_W, out_W, enc_emb, wihf, wihb, whhf, whhb,
                                      dec_emb, dec_wih, dec_whh,
                                      WhT_sw, outWT_sw, whhf_sw, whhb_sw,
                                      decwih_sw, decwhh_sw, WeT, emb16,
                                      wihf16, wihb16, decemb16, out);
    k_vocab<<<16, 256, 0, stream>>>(emb16, wihf16, wihb16, bf_, bb_, xg_vocab);
    k_enc<<<16, 512, 0, stream>>>(src, xg_vocab, whhf_sw, whhb_sw, enc_out, hdec0, c_ws);
    k_proj<<<2048, 256, 0, stream>>>(enc_out, WeT, proj8);
    k_qinit<<<16, 256, 0, stream>>>(hdec0, WhT_sw, qpart);

    // decode: one launch per step (gates for t-1 fused ahead of attention t)
    for (int tt = 0; tt < 127; ++tt)
        k_step<<<288, 512, 0, stream>>>(proj8, enc_out, qpart, attn_b, attn_v,
                                        trg, decemb16, x_sw, part_m, part_l,
                                        part_ctx, hdec0, hdec1, decwih_sw,
                                        decwhh_sw, dec_b, c_ws, hhist_sw,
                                        WhT_sw, flagsv, tt);
    // trailing gates for the last step (t=126): hprev = hdec0, hnext = hdec1
    k_gates<<<32, 256, 0, stream>>>(x_sw, hdec0, decwih_sw, decwhh_sw, dec_b,
                                    c_ws, hdec1, hhist_sw, WhT_sw, qpart,
                                    part_m, part_l, part_ctx, 126);

    k_logits<<<127, 256, 0, stream>>>(hhist_sw, outWT_sw, out_b, out);
}